// Round 1
// baseline (1341.496 us; speedup 1.0000x reference)
//
#include <hip/hip_runtime.h>
#include <hip/hip_bf16.h>

#define N_NODES 100000
#define N_EDGES 1600000
#define F_IN 64
#define HID 128
#define HEAD_H 256
#define OUT_F 32
#define N_GRAPHS 512

__device__ __forceinline__ float leaky(float v) {
    return v >= 0.f ? v : 0.01f * v;
}

// ---------------- CSR build ----------------

__global__ __launch_bounds__(256) void hist_kernel(const int* __restrict__ dst, int* __restrict__ cnt) {
    int e = blockIdx.x * 256 + threadIdx.x;
    if (e < N_EDGES) atomicAdd(&cnt[dst[e]], 1);
}

// single-block inclusive->exclusive scan over N_NODES, writes rowptr[N_NODES+1]
__global__ __launch_bounds__(1024) void scan_kernel(const int* __restrict__ cnt, int* __restrict__ rowptr) {
    __shared__ int sdata[1024];
    __shared__ int s_running;
    if (threadIdx.x == 0) s_running = 0;
    __syncthreads();
    for (int base = 0; base < N_NODES; base += 1024) {
        int i = base + (int)threadIdx.x;
        int v = (i < N_NODES) ? cnt[i] : 0;
        sdata[threadIdx.x] = v;
        __syncthreads();
        for (int off = 1; off < 1024; off <<= 1) {
            int t = (threadIdx.x >= off) ? sdata[threadIdx.x - off] : 0;
            __syncthreads();
            sdata[threadIdx.x] += t;
            __syncthreads();
        }
        int incl = sdata[threadIdx.x];
        int excl = incl - v;
        if (i < N_NODES) rowptr[i] = s_running + excl;
        int total = sdata[1023];
        __syncthreads();
        if (threadIdx.x == 0) s_running += total;
        __syncthreads();
    }
    if (threadIdx.x == 0) rowptr[N_NODES] = s_running;
}

__global__ __launch_bounds__(256) void scatter_kernel(const int* __restrict__ dst,
                                                      const int* __restrict__ rowptr,
                                                      int* __restrict__ cursor,
                                                      int* __restrict__ eidx) {
    int e = blockIdx.x * 256 + threadIdx.x;
    if (e < N_EDGES) {
        int d = dst[e];
        int pos = atomicAdd(&cursor[d], 1);
        eidx[rowptr[d] + pos] = e;
    }
}

// ---------------- GINE edge gather (one wave per node) ----------------
// agg[n][:] = sum over incoming edges e (src s): relu(xin[s][:] + ea0*We[0][:] + ea1*We[1][:] + be[:])

template <int D>
__global__ __launch_bounds__(256) void gine_gather(const float* __restrict__ xin,
                                                   const int* __restrict__ src,
                                                   const float* __restrict__ ea,
                                                   const int* __restrict__ rowptr,
                                                   const int* __restrict__ eidx,
                                                   const float* __restrict__ We,
                                                   const float* __restrict__ be,
                                                   float* __restrict__ agg) {
    constexpr int VPL = D / 64;  // values per lane
    int wave = (blockIdx.x * 256 + (int)threadIdx.x) >> 6;
    int lane = threadIdx.x & 63;
    if (wave >= N_NODES) return;

    float w0[VPL], w1[VPL], bb[VPL], acc[VPL];
#pragma unroll
    for (int v = 0; v < VPL; v++) {
        int j = lane * VPL + v;
        w0[v] = We[j];
        w1[v] = We[D + j];
        bb[v] = be[j];
        acc[v] = 0.f;
    }

    int rs = rowptr[wave];
    int re = rowptr[wave + 1];
    const float2* eap = (const float2*)ea;
    for (int t = rs; t < re; t++) {
        int e = eidx[t];
        int s = src[e];
        float2 a = eap[e];
        const float* xr = xin + (size_t)s * D + lane * VPL;
#pragma unroll
        for (int v = 0; v < VPL; v++) {
            float m = xr[v] + a.x * w0[v] + a.y * w1[v] + bb[v];
            acc[v] += fmaxf(m, 0.f);
        }
    }
    float* ar = agg + (size_t)wave * D + lane * VPL;
#pragma unroll
    for (int v = 0; v < VPL; v++) ar[v] = acc[v];
}

// ---------------- node transform: out[n][:] = leaky((agg[n]+xin[n]) @ Wn + bn) ----------------
// out may alias agg (rows staged to LDS before writes). NPB nodes per block, 128 threads.

template <int DIN, int NPB>
__global__ __launch_bounds__(128) void gine_transform(const float* __restrict__ agg,
                                                      const float* __restrict__ xin,
                                                      const float* __restrict__ Wn,
                                                      const float* __restrict__ bn,
                                                      float* __restrict__ out) {
    __shared__ float t[NPB][DIN];
    int node0 = blockIdx.x * NPB;
    int j = threadIdx.x;  // output feature 0..127

    for (int idx = (int)threadIdx.x; idx < NPB * DIN; idx += 128) {
        int m = idx / DIN;
        int k = idx % DIN;
        size_t off = (size_t)(node0 + m) * DIN + k;
        t[m][k] = agg[off] + xin[off];
    }
    __syncthreads();

    float acc[NPB];
#pragma unroll
    for (int m = 0; m < NPB; m++) acc[m] = bn[j];
    for (int k = 0; k < DIN; k++) {
        float w = Wn[k * HID + j];
#pragma unroll
        for (int m = 0; m < NPB; m++) acc[m] += t[m][k] * w;
    }
#pragma unroll
    for (int m = 0; m < NPB; m++) {
        out[(size_t)(node0 + m) * HID + j] = leaky(acc[m]);
    }
}

// ---------------- pooling: batch is sorted; one block per graph ----------------

__global__ __launch_bounds__(128) void pool_kernel(const float* __restrict__ h,
                                                   const int* __restrict__ batch,
                                                   float* __restrict__ pooled) {
    int g = blockIdx.x;
    int lo = 0, hi = N_NODES;
    while (lo < hi) { int m = (lo + hi) >> 1; if (batch[m] < g) lo = m + 1; else hi = m; }
    int start = lo;
    lo = 0; hi = N_NODES;
    while (lo < hi) { int m = (lo + hi) >> 1; if (batch[m] < g + 1) lo = m + 1; else hi = m; }
    int end = lo;

    int j = threadIdx.x;
    float acc = 0.f;
    for (int i = start; i < end; i++) acc += h[(size_t)i * HID + j];
    pooled[g * HID + j] = acc;
}

// ---------------- head MLP: leaky(pooled@Wh0+bh0) @ Wh1 + bh1 ----------------

__global__ __launch_bounds__(256) void head_kernel(const float* __restrict__ pooled,
                                                   const float* __restrict__ Wh0,
                                                   const float* __restrict__ bh0,
                                                   const float* __restrict__ Wh1,
                                                   const float* __restrict__ bh1,
                                                   float* __restrict__ out) {
    __shared__ float p[HID];
    __shared__ float hid[HEAD_H];
    int g = blockIdx.x;
    int t = threadIdx.x;
    if (t < HID) p[t] = pooled[g * HID + t];
    __syncthreads();
    float acc = bh0[t];
    for (int k = 0; k < HID; k++) acc += p[k] * Wh0[k * HEAD_H + t];
    hid[t] = leaky(acc);
    __syncthreads();
    if (t < OUT_F) {
        float o = bh1[t];
        for (int k = 0; k < HEAD_H; k++) o += hid[k] * Wh1[k * OUT_F + t];
        out[g * OUT_F + t] = o;
    }
}

extern "C" void kernel_launch(void* const* d_in, const int* in_sizes, int n_in,
                              void* d_out, int out_size, void* d_ws, size_t ws_size,
                              hipStream_t stream) {
    const float* x     = (const float*)d_in[0];
    const int*   ei    = (const int*)d_in[1];
    const float* ea    = (const float*)d_in[2];
    const int*   batch = (const int*)d_in[3];
    const float* We0 = (const float*)d_in[4];
    const float* be0 = (const float*)d_in[5];
    const float* Wn0 = (const float*)d_in[6];
    const float* bn0 = (const float*)d_in[7];
    const float* We1 = (const float*)d_in[8];
    const float* be1 = (const float*)d_in[9];
    const float* Wn1 = (const float*)d_in[10];
    const float* bn1 = (const float*)d_in[11];
    const float* We2 = (const float*)d_in[12];
    const float* be2 = (const float*)d_in[13];
    const float* Wn2 = (const float*)d_in[14];
    const float* bn2 = (const float*)d_in[15];
    const float* Wh0 = (const float*)d_in[16];
    const float* bh0 = (const float*)d_in[17];
    const float* Wh1 = (const float*)d_in[18];
    const float* bh1 = (const float*)d_in[19];

    const int* src = ei;
    const int* dst = ei + N_EDGES;

    char* ws = (char*)d_ws;
    const size_t BUF_BYTES = (size_t)N_NODES * HID * sizeof(float);  // 51.2e6
    float* bufA   = (float*)(ws);
    float* bufB   = (float*)(ws + BUF_BYTES);
    int*   rowptr = (int*)(ws + 2 * BUF_BYTES);
    int*   cnt    = (int*)(ws + 2 * BUF_BYTES + 400384);
    int*   eidx   = (int*)(ws + 2 * BUF_BYTES + 2 * 400384);
    float* pooled = (float*)(ws + 2 * BUF_BYTES + 2 * 400384 + (size_t)N_EDGES * 4);

    // --- CSR build (by dst) ---
    hipMemsetAsync(cnt, 0, N_NODES * sizeof(int), stream);
    hist_kernel<<<N_EDGES / 256, 256, 0, stream>>>(dst, cnt);
    scan_kernel<<<1, 1024, 0, stream>>>(cnt, rowptr);
    hipMemsetAsync(cnt, 0, N_NODES * sizeof(int), stream);
    scatter_kernel<<<N_EDGES / 256, 256, 0, stream>>>(dst, rowptr, cnt, eidx);

    const int GATHER_BLOCKS = (N_NODES * 64 + 255) / 256;   // 25000
    const int TRANS_BLOCKS  = N_NODES / 8;                  // 12500

    // --- layer 0 (64 -> 128) ---
    gine_gather<64><<<GATHER_BLOCKS, 256, 0, stream>>>(x, src, ea, rowptr, eidx, We0, be0, bufA);
    gine_transform<64, 8><<<TRANS_BLOCKS, 128, 0, stream>>>(bufA, x, Wn0, bn0, bufB);

    // --- layer 1 (128 -> 128) ---
    gine_gather<128><<<GATHER_BLOCKS, 256, 0, stream>>>(bufB, src, ea, rowptr, eidx, We1, be1, bufA);
    gine_transform<128, 8><<<TRANS_BLOCKS, 128, 0, stream>>>(bufA, bufB, Wn1, bn1, bufA);

    // --- layer 2 (128 -> 128) ---
    gine_gather<128><<<GATHER_BLOCKS, 256, 0, stream>>>(bufA, src, ea, rowptr, eidx, We2, be2, bufB);
    gine_transform<128, 8><<<TRANS_BLOCKS, 128, 0, stream>>>(bufB, bufA, Wn2, bn2, bufB);

    // --- pool + head ---
    pool_kernel<<<N_GRAPHS, 128, 0, stream>>>(bufB, batch, pooled);
    head_kernel<<<N_GRAPHS, 256, 0, stream>>>(pooled, Wh0, bh0, Wh1, bh1, (float*)d_out);
}

// Round 2
// 909.196 us; speedup vs baseline: 1.4755x; 1.4755x over previous
//
#include <hip/hip_runtime.h>
#include <hip/hip_bf16.h>

#define N_NODES 100000
#define N_EDGES 1600000
#define F_IN 64
#define HID 128
#define HEAD_H 256
#define OUT_F 32
#define N_GRAPHS 512

__device__ __forceinline__ float leaky(float v) {
    return v >= 0.f ? v : 0.01f * v;
}

__device__ __forceinline__ float bf2f(ushort u) {
    union { uint i; float f; } c; c.i = ((uint)u) << 16; return c.f;
}

__device__ __forceinline__ ushort f2bf(float f) {
    union { float f; uint i; } c; c.f = f;
    uint r = c.i + 0x7FFF + ((c.i >> 16) & 1);
    return (ushort)(r >> 16);
}

// ---------------- cast x -> bf16 ----------------
__global__ __launch_bounds__(256) void cast_kernel(const float* __restrict__ x,
                                                   ushort* __restrict__ xb, int n2) {
    int i = blockIdx.x * 256 + threadIdx.x;  // handles 2 elems
    if (i < n2) {
        float2 v = ((const float2*)x)[i];
        uint u = (uint)f2bf(v.x) | ((uint)f2bf(v.y) << 16);
        ((uint*)xb)[i] = u;
    }
}

// ---------------- CSR build ----------------

__global__ __launch_bounds__(256) void hist_kernel(const int* __restrict__ dst, int* __restrict__ cnt) {
    int e = blockIdx.x * 256 + threadIdx.x;
    if (e < N_EDGES) atomicAdd(&cnt[dst[e]], 1);
}

// single-block scan: per-thread serial chunk + one ladder
__global__ __launch_bounds__(1024) void scan_kernel(const int* __restrict__ cnt, int* __restrict__ rowptr) {
    __shared__ int ssum[1024];
    const int CH = (N_NODES + 1023) / 1024;  // 98
    int tid = threadIdx.x;
    int begin = tid * CH;
    int end = begin + CH; if (end > N_NODES) end = N_NODES;
    int s = 0;
    for (int i = begin; i < end; i++) s += cnt[i];
    ssum[tid] = s;
    __syncthreads();
    for (int off = 1; off < 1024; off <<= 1) {
        int t = (tid >= off) ? ssum[tid - off] : 0;
        __syncthreads();
        ssum[tid] += t;
        __syncthreads();
    }
    int prefix = ssum[tid] - s;  // exclusive
    for (int i = begin; i < end; i++) {
        rowptr[i] = prefix;
        prefix += cnt[i];
    }
    if (tid == 1023) rowptr[N_NODES] = ssum[1023];
}

// scatter packed records {src, ea.x, ea.y, 0} in CSR(dst) order
__global__ __launch_bounds__(256) void scatter_kernel(const int* __restrict__ src,
                                                      const int* __restrict__ dst,
                                                      const float2* __restrict__ ea,
                                                      const int* __restrict__ rowptr,
                                                      int* __restrict__ cursor,
                                                      int4* __restrict__ recs) {
    int e = blockIdx.x * 256 + threadIdx.x;
    if (e < N_EDGES) {
        int d = dst[e];
        int pos = atomicAdd(&cursor[d], 1);
        float2 a = ea[e];
        recs[rowptr[d] + pos] = make_int4(src[e], __float_as_int(a.x), __float_as_int(a.y), 0);
    }
}

// ---------------- GINE edge gather (one wave per node), bf16 features ----------------
// tb[n][:] = xb[n][:] + sum_e relu(xb[src_e][:] + ea0*We[0] + ea1*We[1] + be)

template <int VPL>
__device__ __forceinline__ void load_row(const ushort* __restrict__ xb, int s, int lane, float* x) {
    if constexpr (VPL == 1) {
        x[0] = bf2f(xb[(size_t)s * 64 + lane]);
    } else {
        uint u = *(const uint*)(xb + (size_t)s * 128 + lane * 2);
        x[0] = bf2f((ushort)(u & 0xFFFF));
        x[1] = bf2f((ushort)(u >> 16));
    }
}

template <int D>
__global__ __launch_bounds__(256) void gine_gather(const ushort* __restrict__ xb,
                                                   const int4* __restrict__ recs,
                                                   const int* __restrict__ rowptr,
                                                   const float* __restrict__ We,
                                                   const float* __restrict__ be,
                                                   ushort* __restrict__ tb) {
    constexpr int VPL = D / 64;
    int node = (blockIdx.x * 256 + (int)threadIdx.x) >> 6;
    int lane = threadIdx.x & 63;
    if (node >= N_NODES) return;

    float w0[VPL], w1[VPL], bb[VPL], acc[VPL];
#pragma unroll
    for (int v = 0; v < VPL; v++) {
        int j = lane * VPL + v;
        w0[v] = We[j];
        w1[v] = We[D + j];
        bb[v] = be[j];
        acc[v] = 0.f;
    }

    int rs = rowptr[node];
    int re = rowptr[node + 1];

    int t = rs;
    for (; t + 1 < re; t += 2) {
        int4 rA = recs[t];
        int4 rB = recs[t + 1];
        float xA[VPL], xB[VPL];
        load_row<VPL>(xb, rA.x, lane, xA);
        load_row<VPL>(xb, rB.x, lane, xB);
        float aAx = __int_as_float(rA.y), aAy = __int_as_float(rA.z);
        float aBx = __int_as_float(rB.y), aBy = __int_as_float(rB.z);
#pragma unroll
        for (int v = 0; v < VPL; v++) {
            acc[v] += fmaxf(xA[v] + aAx * w0[v] + aAy * w1[v] + bb[v], 0.f);
            acc[v] += fmaxf(xB[v] + aBx * w0[v] + aBy * w1[v] + bb[v], 0.f);
        }
    }
    if (t < re) {
        int4 rA = recs[t];
        float xA[VPL];
        load_row<VPL>(xb, rA.x, lane, xA);
        float aAx = __int_as_float(rA.y), aAy = __int_as_float(rA.z);
#pragma unroll
        for (int v = 0; v < VPL; v++) {
            acc[v] += fmaxf(xA[v] + aAx * w0[v] + aAy * w1[v] + bb[v], 0.f);
        }
    }

    // residual
    float xr[VPL];
    load_row<VPL>(xb, node, lane, xr);
#pragma unroll
    for (int v = 0; v < VPL; v++) acc[v] += xr[v];

    if constexpr (VPL == 1) {
        tb[(size_t)node * 64 + lane] = f2bf(acc[0]);
    } else {
        uint u = (uint)f2bf(acc[0]) | ((uint)f2bf(acc[1]) << 16);
        ((uint*)tb)[(size_t)node * 64 + lane] = u;
    }
}

// ---------------- node transform: hb = leaky(tb @ Wn + bn), bf16 in/out ----------------

template <int DIN, int NPB>
__global__ __launch_bounds__(128) void gine_transform(const ushort* __restrict__ tb,
                                                      const float* __restrict__ Wn,
                                                      const float* __restrict__ bn,
                                                      ushort* __restrict__ hb) {
    __shared__ float tt[NPB][DIN];
    int node0 = blockIdx.x * NPB;
    int j = threadIdx.x;  // output feature 0..127

    const uint* tsrc = (const uint*)(tb + (size_t)node0 * DIN);
    for (int idx = (int)threadIdx.x; idx < NPB * DIN / 2; idx += 128) {
        uint u = tsrc[idx];
        int base = idx * 2;
        tt[base / DIN][base % DIN] = bf2f((ushort)(u & 0xFFFF));
        tt[base / DIN][base % DIN + 1] = bf2f((ushort)(u >> 16));
    }
    __syncthreads();

    float acc[NPB];
#pragma unroll
    for (int m = 0; m < NPB; m++) acc[m] = bn[j];
    for (int k = 0; k < DIN; k += 4) {
        float wq0 = Wn[(k + 0) * HID + j];
        float wq1 = Wn[(k + 1) * HID + j];
        float wq2 = Wn[(k + 2) * HID + j];
        float wq3 = Wn[(k + 3) * HID + j];
#pragma unroll
        for (int m = 0; m < NPB; m++) {
            float4 tv = *(const float4*)&tt[m][k];
            acc[m] += tv.x * wq0 + tv.y * wq1 + tv.z * wq2 + tv.w * wq3;
        }
    }
#pragma unroll
    for (int m = 0; m < NPB; m++) {
        hb[(size_t)(node0 + m) * HID + j] = f2bf(leaky(acc[m]));
    }
}

// ---------------- pooling: batch is sorted; one block per graph ----------------

__global__ __launch_bounds__(128) void pool_kernel(const ushort* __restrict__ h,
                                                   const int* __restrict__ batch,
                                                   float* __restrict__ pooled) {
    int g = blockIdx.x;
    int lo = 0, hi = N_NODES;
    while (lo < hi) { int m = (lo + hi) >> 1; if (batch[m] < g) lo = m + 1; else hi = m; }
    int start = lo;
    lo = 0; hi = N_NODES;
    while (lo < hi) { int m = (lo + hi) >> 1; if (batch[m] < g + 1) lo = m + 1; else hi = m; }
    int end = lo;

    int j = threadIdx.x;
    float acc = 0.f;
    for (int i = start; i < end; i++) acc += bf2f(h[(size_t)i * HID + j]);
    pooled[g * HID + j] = acc;
}

// ---------------- head MLP ----------------

__global__ __launch_bounds__(256) void head_kernel(const float* __restrict__ pooled,
                                                   const float* __restrict__ Wh0,
                                                   const float* __restrict__ bh0,
                                                   const float* __restrict__ Wh1,
                                                   const float* __restrict__ bh1,
                                                   float* __restrict__ out) {
    __shared__ float p[HID];
    __shared__ float hid[HEAD_H];
    int g = blockIdx.x;
    int t = threadIdx.x;
    if (t < HID) p[t] = pooled[g * HID + t];
    __syncthreads();
    float acc = bh0[t];
    for (int k = 0; k < HID; k++) acc += p[k] * Wh0[k * HEAD_H + t];
    hid[t] = leaky(acc);
    __syncthreads();
    if (t < OUT_F) {
        float o = bh1[t];
        for (int k = 0; k < HEAD_H; k++) o += hid[k] * Wh1[k * OUT_F + t];
        out[g * OUT_F + t] = o;
    }
}

extern "C" void kernel_launch(void* const* d_in, const int* in_sizes, int n_in,
                              void* d_out, int out_size, void* d_ws, size_t ws_size,
                              hipStream_t stream) {
    const float* x     = (const float*)d_in[0];
    const int*   ei    = (const int*)d_in[1];
    const float* ea    = (const float*)d_in[2];
    const int*   batch = (const int*)d_in[3];
    const float* We0 = (const float*)d_in[4];
    const float* be0 = (const float*)d_in[5];
    const float* Wn0 = (const float*)d_in[6];
    const float* bn0 = (const float*)d_in[7];
    const float* We1 = (const float*)d_in[8];
    const float* be1 = (const float*)d_in[9];
    const float* Wn1 = (const float*)d_in[10];
    const float* bn1 = (const float*)d_in[11];
    const float* We2 = (const float*)d_in[12];
    const float* be2 = (const float*)d_in[13];
    const float* Wn2 = (const float*)d_in[14];
    const float* bn2 = (const float*)d_in[15];
    const float* Wh0 = (const float*)d_in[16];
    const float* bh0 = (const float*)d_in[17];
    const float* Wh1 = (const float*)d_in[18];
    const float* bh1 = (const float*)d_in[19];

    const int* src = ei;
    const int* dst = ei + N_EDGES;

    char* ws = (char*)d_ws;
    size_t o = 0;
    int4*   recs = (int4*)(ws + o);   o += (size_t)N_EDGES * 16;          // 25.6 MB
    ushort* xb0  = (ushort*)(ws + o); o += (size_t)N_NODES * 64 * 2;      // 12.8 MB
    ushort* tbuf = (ushort*)(ws + o); o += (size_t)N_NODES * 128 * 2;     // 25.6 MB
    ushort* hbuf = (ushort*)(ws + o); o += (size_t)N_NODES * 128 * 2;     // 25.6 MB
    int*    rowptr = (int*)(ws + o);  o += 400128;
    int*    cnt    = (int*)(ws + o);  o += 400128;
    float*  pooled = (float*)(ws + o);

    // --- cast x to bf16 ---
    cast_kernel<<<(N_NODES * F_IN / 2 + 255) / 256, 256, 0, stream>>>(x, xb0, N_NODES * F_IN / 2);

    // --- CSR build (by dst) ---
    hipMemsetAsync(cnt, 0, N_NODES * sizeof(int), stream);
    hist_kernel<<<N_EDGES / 256, 256, 0, stream>>>(dst, cnt);
    scan_kernel<<<1, 1024, 0, stream>>>(cnt, rowptr);
    hipMemsetAsync(cnt, 0, N_NODES * sizeof(int), stream);
    scatter_kernel<<<N_EDGES / 256, 256, 0, stream>>>(src, dst, (const float2*)ea, rowptr, cnt, recs);

    const int GATHER_BLOCKS = (N_NODES * 64 + 255) / 256;   // 25000
    const int TRANS_BLOCKS  = N_NODES / 8;                  // 12500

    // --- layer 0 (64 -> 128) ---
    gine_gather<64><<<GATHER_BLOCKS, 256, 0, stream>>>(xb0, recs, rowptr, We0, be0, tbuf);
    gine_transform<64, 8><<<TRANS_BLOCKS, 128, 0, stream>>>(tbuf, Wn0, bn0, hbuf);

    // --- layer 1 (128 -> 128) ---
    gine_gather<128><<<GATHER_BLOCKS, 256, 0, stream>>>(hbuf, recs, rowptr, We1, be1, tbuf);
    gine_transform<128, 8><<<TRANS_BLOCKS, 128, 0, stream>>>(tbuf, Wn1, bn1, hbuf);

    // --- layer 2 (128 -> 128) ---
    gine_gather<128><<<GATHER_BLOCKS, 256, 0, stream>>>(hbuf, recs, rowptr, We2, be2, tbuf);
    gine_transform<128, 8><<<TRANS_BLOCKS, 128, 0, stream>>>(tbuf, Wn2, bn2, hbuf);

    // --- pool + head ---
    pool_kernel<<<N_GRAPHS, 128, 0, stream>>>(hbuf, batch, pooled);
    head_kernel<<<N_GRAPHS, 256, 0, stream>>>(pooled, Wh0, bh0, Wh1, bh1, (float*)d_out);
}

// Round 3
// 694.684 us; speedup vs baseline: 1.9311x; 1.3088x over previous
//
#include <hip/hip_runtime.h>
#include <hip/hip_bf16.h>

#define N_NODES 100000
#define N_EDGES 1600000
#define F_IN 64
#define HID 128
#define HEAD_H 256
#define OUT_F 32
#define N_GRAPHS 512
#define NB_SCAN 98  // ceil(N_NODES / 1024)

__device__ __forceinline__ float leaky(float v) {
    return v >= 0.f ? v : 0.01f * v;
}

__device__ __forceinline__ float bf2f(ushort u) {
    union { uint i; float f; } c; c.i = ((uint)u) << 16; return c.f;
}

__device__ __forceinline__ ushort f2bf(float f) {
    union { float f; uint i; } c; c.f = f;
    uint r = c.i + 0x7FFF + ((c.i >> 16) & 1);
    return (ushort)(r >> 16);
}

// ---------------- cast x -> bf16 ----------------
__global__ __launch_bounds__(256) void cast_kernel(const float* __restrict__ x,
                                                   ushort* __restrict__ xb, int n2) {
    int i = blockIdx.x * 256 + threadIdx.x;  // handles 2 elems
    if (i < n2) {
        float2 v = ((const float2*)x)[i];
        uint u = (uint)f2bf(v.x) | ((uint)f2bf(v.y) << 16);
        ((uint*)xb)[i] = u;
    }
}

// ---------------- CSR build ----------------

__global__ __launch_bounds__(256) void hist_kernel(const int* __restrict__ dst, int* __restrict__ cnt) {
    int e = blockIdx.x * 256 + threadIdx.x;
    if (e < N_EDGES) atomicAdd(&cnt[dst[e]], 1);
}

// phase 1: per-block (1024 elems) sums
__global__ __launch_bounds__(256) void scan_sums(const int* __restrict__ cnt, int* __restrict__ bsum) {
    __shared__ int sd[256];
    int tid = threadIdx.x;
    int base = blockIdx.x * 1024 + tid * 4;
    int s = 0;
    if (base + 4 <= N_NODES) {
        int4 v = *(const int4*)(cnt + base);
        s = v.x + v.y + v.z + v.w;
    } else {
        for (int i = base; i < N_NODES && i < base + 4; i++) s += cnt[i];
    }
    sd[tid] = s;
    __syncthreads();
    for (int off = 128; off > 0; off >>= 1) {
        if (tid < off) sd[tid] += sd[tid + off];
        __syncthreads();
    }
    if (tid == 0) bsum[blockIdx.x] = sd[0];
}

// phase 2: scan the 98 block sums (in place -> exclusive), write rowptr[N]
__global__ __launch_bounds__(128) void scan_offsets(int* __restrict__ bsum, int* __restrict__ rowptr) {
    __shared__ int sd[128];
    int t = threadIdx.x;
    int v = (t < NB_SCAN) ? bsum[t] : 0;
    sd[t] = v;
    __syncthreads();
    for (int off = 1; off < 128; off <<= 1) {
        int u = (t >= off) ? sd[t - off] : 0;
        __syncthreads();
        sd[t] += u;
        __syncthreads();
    }
    if (t < NB_SCAN) bsum[t] = sd[t] - v;  // exclusive
    if (t == 0) rowptr[N_NODES] = N_EDGES;
}

// phase 3: per-block exclusive scan + block offset -> rowptr
__global__ __launch_bounds__(256) void scan_final(const int* __restrict__ cnt,
                                                  const int* __restrict__ boff,
                                                  int* __restrict__ rowptr) {
    __shared__ int sd[256];
    int tid = threadIdx.x;
    int base = blockIdx.x * 1024 + tid * 4;
    bool full = (base + 4 <= N_NODES);
    int4 v = make_int4(0, 0, 0, 0);
    if (full) {
        v = *(const int4*)(cnt + base);
    } else {
        if (base + 0 < N_NODES) v.x = cnt[base + 0];
        if (base + 1 < N_NODES) v.y = cnt[base + 1];
        if (base + 2 < N_NODES) v.z = cnt[base + 2];
        if (base + 3 < N_NODES) v.w = cnt[base + 3];
    }
    int s = v.x + v.y + v.z + v.w;
    sd[tid] = s;
    __syncthreads();
    for (int off = 1; off < 256; off <<= 1) {
        int u = (tid >= off) ? sd[tid - off] : 0;
        __syncthreads();
        sd[tid] += u;
        __syncthreads();
    }
    int pre = sd[tid] - s + boff[blockIdx.x];
    int4 w;
    w.x = pre;
    w.y = pre + v.x;
    w.z = pre + v.x + v.y;
    w.w = pre + v.x + v.y + v.z;
    if (full) {
        *(int4*)(rowptr + base) = w;
    } else {
        if (base + 0 < N_NODES) rowptr[base + 0] = w.x;
        if (base + 1 < N_NODES) rowptr[base + 1] = w.y;
        if (base + 2 < N_NODES) rowptr[base + 2] = w.z;
        if (base + 3 < N_NODES) rowptr[base + 3] = w.w;
    }
}

// scatter packed records {src, ea.x, ea.y, 0} in CSR(dst) order
__global__ __launch_bounds__(256) void scatter_kernel(const int* __restrict__ src,
                                                      const int* __restrict__ dst,
                                                      const float2* __restrict__ ea,
                                                      const int* __restrict__ rowptr,
                                                      int* __restrict__ cursor,
                                                      int4* __restrict__ recs) {
    int e = blockIdx.x * 256 + threadIdx.x;
    if (e < N_EDGES) {
        int d = dst[e];
        int pos = atomicAdd(&cursor[d], 1);
        float2 a = ea[e];
        recs[rowptr[d] + pos] = make_int4(src[e], __float_as_int(a.x), __float_as_int(a.y), 0);
    }
}

// ---------------- GINE edge gather (one wave per node), bf16 features ----------------
// tb[n][:] = xb[n][:] + sum_e relu(xb[src_e][:] + ea0*We[0] + ea1*We[1] + be)

template <int VPL>
__device__ __forceinline__ void load_row(const ushort* __restrict__ xb, int s, int lane, float* x) {
    if constexpr (VPL == 1) {
        x[0] = bf2f(xb[(size_t)s * 64 + lane]);
    } else {
        uint u = *(const uint*)(xb + (size_t)s * 128 + lane * 2);
        x[0] = bf2f((ushort)(u & 0xFFFF));
        x[1] = bf2f((ushort)(u >> 16));
    }
}

template <int D>
__global__ __launch_bounds__(256) void gine_gather(const ushort* __restrict__ xb,
                                                   const int4* __restrict__ recs,
                                                   const int* __restrict__ rowptr,
                                                   const float* __restrict__ We,
                                                   const float* __restrict__ be,
                                                   ushort* __restrict__ tb) {
    constexpr int VPL = D / 64;
    int node = (blockIdx.x * 256 + (int)threadIdx.x) >> 6;
    int lane = threadIdx.x & 63;
    if (node >= N_NODES) return;

    float w0[VPL], w1[VPL], bb[VPL], acc[VPL];
#pragma unroll
    for (int v = 0; v < VPL; v++) {
        int j = lane * VPL + v;
        w0[v] = We[j];
        w1[v] = We[D + j];
        bb[v] = be[j];
        acc[v] = 0.f;
    }

    int rs = rowptr[node];
    int re = rowptr[node + 1];

    int t = rs;
    for (; t + 3 < re; t += 4) {
        int4 r0 = recs[t];
        int4 r1 = recs[t + 1];
        int4 r2 = recs[t + 2];
        int4 r3 = recs[t + 3];
        float x0[VPL], x1[VPL], x2[VPL], x3[VPL];
        load_row<VPL>(xb, r0.x, lane, x0);
        load_row<VPL>(xb, r1.x, lane, x1);
        load_row<VPL>(xb, r2.x, lane, x2);
        load_row<VPL>(xb, r3.x, lane, x3);
        float a0x = __int_as_float(r0.y), a0y = __int_as_float(r0.z);
        float a1x = __int_as_float(r1.y), a1y = __int_as_float(r1.z);
        float a2x = __int_as_float(r2.y), a2y = __int_as_float(r2.z);
        float a3x = __int_as_float(r3.y), a3y = __int_as_float(r3.z);
#pragma unroll
        for (int v = 0; v < VPL; v++) {
            acc[v] += fmaxf(x0[v] + a0x * w0[v] + a0y * w1[v] + bb[v], 0.f);
            acc[v] += fmaxf(x1[v] + a1x * w0[v] + a1y * w1[v] + bb[v], 0.f);
            acc[v] += fmaxf(x2[v] + a2x * w0[v] + a2y * w1[v] + bb[v], 0.f);
            acc[v] += fmaxf(x3[v] + a3x * w0[v] + a3y * w1[v] + bb[v], 0.f);
        }
    }
    for (; t < re; t++) {
        int4 rA = recs[t];
        float xA[VPL];
        load_row<VPL>(xb, rA.x, lane, xA);
        float aAx = __int_as_float(rA.y), aAy = __int_as_float(rA.z);
#pragma unroll
        for (int v = 0; v < VPL; v++) {
            acc[v] += fmaxf(xA[v] + aAx * w0[v] + aAy * w1[v] + bb[v], 0.f);
        }
    }

    // residual
    float xr[VPL];
    load_row<VPL>(xb, node, lane, xr);
#pragma unroll
    for (int v = 0; v < VPL; v++) acc[v] += xr[v];

    if constexpr (VPL == 1) {
        tb[(size_t)node * 64 + lane] = f2bf(acc[0]);
    } else {
        uint u = (uint)f2bf(acc[0]) | ((uint)f2bf(acc[1]) << 16);
        ((uint*)tb)[(size_t)node * 64 + lane] = u;
    }
}

// ---------------- node transform: hb = leaky(tb @ Wn + bn), bf16 in/out ----------------

template <int DIN, int NPB>
__global__ __launch_bounds__(128) void gine_transform(const ushort* __restrict__ tb,
                                                      const float* __restrict__ Wn,
                                                      const float* __restrict__ bn,
                                                      ushort* __restrict__ hb) {
    __shared__ float tt[NPB][DIN];
    int node0 = blockIdx.x * NPB;
    int j = threadIdx.x;  // output feature 0..127

    const uint* tsrc = (const uint*)(tb + (size_t)node0 * DIN);
    for (int idx = (int)threadIdx.x; idx < NPB * DIN / 2; idx += 128) {
        uint u = tsrc[idx];
        int base = idx * 2;
        tt[base / DIN][base % DIN] = bf2f((ushort)(u & 0xFFFF));
        tt[base / DIN][base % DIN + 1] = bf2f((ushort)(u >> 16));
    }
    __syncthreads();

    float acc[NPB];
#pragma unroll
    for (int m = 0; m < NPB; m++) acc[m] = bn[j];
    for (int k = 0; k < DIN; k += 4) {
        float wq0 = Wn[(k + 0) * HID + j];
        float wq1 = Wn[(k + 1) * HID + j];
        float wq2 = Wn[(k + 2) * HID + j];
        float wq3 = Wn[(k + 3) * HID + j];
#pragma unroll
        for (int m = 0; m < NPB; m++) {
            float4 tv = *(const float4*)&tt[m][k];
            acc[m] += tv.x * wq0 + tv.y * wq1 + tv.z * wq2 + tv.w * wq3;
        }
    }
#pragma unroll
    for (int m = 0; m < NPB; m++) {
        hb[(size_t)(node0 + m) * HID + j] = f2bf(leaky(acc[m]));
    }
}

// ---------------- pooling: batch is sorted; one block per graph ----------------

__global__ __launch_bounds__(128) void pool_kernel(const ushort* __restrict__ h,
                                                   const int* __restrict__ batch,
                                                   float* __restrict__ pooled) {
    int g = blockIdx.x;
    int lo = 0, hi = N_NODES;
    while (lo < hi) { int m = (lo + hi) >> 1; if (batch[m] < g) lo = m + 1; else hi = m; }
    int start = lo;
    lo = 0; hi = N_NODES;
    while (lo < hi) { int m = (lo + hi) >> 1; if (batch[m] < g + 1) lo = m + 1; else hi = m; }
    int end = lo;

    int j = threadIdx.x;
    float acc = 0.f;
    for (int i = start; i < end; i++) acc += bf2f(h[(size_t)i * HID + j]);
    pooled[g * HID + j] = acc;
}

// ---------------- head MLP ----------------

__global__ __launch_bounds__(256) void head_kernel(const float* __restrict__ pooled,
                                                   const float* __restrict__ Wh0,
                                                   const float* __restrict__ bh0,
                                                   const float* __restrict__ Wh1,
                                                   const float* __restrict__ bh1,
                                                   float* __restrict__ out) {
    __shared__ float p[HID];
    __shared__ float hid[HEAD_H];
    int g = blockIdx.x;
    int t = threadIdx.x;
    if (t < HID) p[t] = pooled[g * HID + t];
    __syncthreads();
    float acc = bh0[t];
    for (int k = 0; k < HID; k++) acc += p[k] * Wh0[k * HEAD_H + t];
    hid[t] = leaky(acc);
    __syncthreads();
    if (t < OUT_F) {
        float o = bh1[t];
        for (int k = 0; k < HEAD_H; k++) o += hid[k] * Wh1[k * OUT_F + t];
        out[g * OUT_F + t] = o;
    }
}

extern "C" void kernel_launch(void* const* d_in, const int* in_sizes, int n_in,
                              void* d_out, int out_size, void* d_ws, size_t ws_size,
                              hipStream_t stream) {
    const float* x     = (const float*)d_in[0];
    const int*   ei    = (const int*)d_in[1];
    const float* ea    = (const float*)d_in[2];
    const int*   batch = (const int*)d_in[3];
    const float* We0 = (const float*)d_in[4];
    const float* be0 = (const float*)d_in[5];
    const float* Wn0 = (const float*)d_in[6];
    const float* bn0 = (const float*)d_in[7];
    const float* We1 = (const float*)d_in[8];
    const float* be1 = (const float*)d_in[9];
    const float* Wn1 = (const float*)d_in[10];
    const float* bn1 = (const float*)d_in[11];
    const float* We2 = (const float*)d_in[12];
    const float* be2 = (const float*)d_in[13];
    const float* Wn2 = (const float*)d_in[14];
    const float* bn2 = (const float*)d_in[15];
    const float* Wh0 = (const float*)d_in[16];
    const float* bh0 = (const float*)d_in[17];
    const float* Wh1 = (const float*)d_in[18];
    const float* bh1 = (const float*)d_in[19];

    const int* src = ei;
    const int* dst = ei + N_EDGES;

    char* ws = (char*)d_ws;
    size_t o = 0;
    int4*   recs = (int4*)(ws + o);   o += (size_t)N_EDGES * 16;          // 25.6 MB
    ushort* xb0  = (ushort*)(ws + o); o += (size_t)N_NODES * 64 * 2;      // 12.8 MB
    ushort* tbuf = (ushort*)(ws + o); o += (size_t)N_NODES * 128 * 2;     // 25.6 MB
    ushort* hbuf = (ushort*)(ws + o); o += (size_t)N_NODES * 128 * 2;     // 25.6 MB
    int*    rowptr = (int*)(ws + o);  o += 400128;
    int*    cnt    = (int*)(ws + o);  o += 400128;
    int*    bsum   = (int*)(ws + o);  o += 4096;
    float*  pooled = (float*)(ws + o);

    // --- cast x to bf16 ---
    cast_kernel<<<(N_NODES * F_IN / 2 + 255) / 256, 256, 0, stream>>>(x, xb0, N_NODES * F_IN / 2);

    // --- CSR build (by dst) ---
    hipMemsetAsync(cnt, 0, N_NODES * sizeof(int), stream);
    hist_kernel<<<N_EDGES / 256, 256, 0, stream>>>(dst, cnt);
    scan_sums<<<NB_SCAN, 256, 0, stream>>>(cnt, bsum);
    scan_offsets<<<1, 128, 0, stream>>>(bsum, rowptr);
    scan_final<<<NB_SCAN, 256, 0, stream>>>(cnt, bsum, rowptr);
    hipMemsetAsync(cnt, 0, N_NODES * sizeof(int), stream);
    scatter_kernel<<<N_EDGES / 256, 256, 0, stream>>>(src, dst, (const float2*)ea, rowptr, cnt, recs);

    const int GATHER_BLOCKS = (N_NODES * 64 + 255) / 256;   // 25000
    const int TRANS_BLOCKS  = N_NODES / 8;                  // 12500

    // --- layer 0 (64 -> 128) ---
    gine_gather<64><<<GATHER_BLOCKS, 256, 0, stream>>>(xb0, recs, rowptr, We0, be0, tbuf);
    gine_transform<64, 8><<<TRANS_BLOCKS, 128, 0, stream>>>(tbuf, Wn0, bn0, hbuf);

    // --- layer 1 (128 -> 128) ---
    gine_gather<128><<<GATHER_BLOCKS, 256, 0, stream>>>(hbuf, recs, rowptr, We1, be1, tbuf);
    gine_transform<128, 8><<<TRANS_BLOCKS, 128, 0, stream>>>(tbuf, Wn1, bn1, hbuf);

    // --- layer 2 (128 -> 128) ---
    gine_gather<128><<<GATHER_BLOCKS, 256, 0, stream>>>(hbuf, recs, rowptr, We2, be2, tbuf);
    gine_transform<128, 8><<<TRANS_BLOCKS, 128, 0, stream>>>(tbuf, Wn2, bn2, hbuf);

    // --- pool + head ---
    pool_kernel<<<N_GRAPHS, 128, 0, stream>>>(hbuf, batch, pooled);
    head_kernel<<<N_GRAPHS, 256, 0, stream>>>(pooled, Wh0, bh0, Wh1, bh1, (float*)d_out);
}

// Round 4
// 663.145 us; speedup vs baseline: 2.0229x; 1.0476x over previous
//
#include <hip/hip_runtime.h>
#include <hip/hip_bf16.h>

#define N_NODES 100000
#define N_EDGES 1600000
#define F_IN 64
#define HID 128
#define HEAD_H 256
#define OUT_F 32
#define N_GRAPHS 512
#define NB_SCAN 98  // ceil(N_NODES / 1024)

__device__ __forceinline__ float leaky(float v) {
    return v >= 0.f ? v : 0.01f * v;
}

__device__ __forceinline__ float bf2f(ushort u) {
    union { uint i; float f; } c; c.i = ((uint)u) << 16; return c.f;
}

__device__ __forceinline__ ushort f2bf(float f) {
    union { float f; uint i; } c; c.f = f;
    uint r = c.i + 0x7FFF + ((c.i >> 16) & 1);
    return (ushort)(r >> 16);
}

// ---------------- cast x -> bf16 ----------------
__global__ __launch_bounds__(256) void cast_kernel(const float* __restrict__ x,
                                                   ushort* __restrict__ xb, int n2) {
    int i = blockIdx.x * 256 + threadIdx.x;  // handles 2 elems
    if (i < n2) {
        float2 v = ((const float2*)x)[i];
        uint u = (uint)f2bf(v.x) | ((uint)f2bf(v.y) << 16);
        ((uint*)xb)[i] = u;
    }
}

// ---------------- CSR build ----------------

__global__ __launch_bounds__(256) void hist_kernel(const int* __restrict__ dst, int* __restrict__ cnt) {
    int e = blockIdx.x * 256 + threadIdx.x;
    if (e < N_EDGES) atomicAdd(&cnt[dst[e]], 1);
}

// phase 1: per-block (1024 elems) sums
__global__ __launch_bounds__(256) void scan_sums(const int* __restrict__ cnt, int* __restrict__ bsum) {
    __shared__ int sd[256];
    int tid = threadIdx.x;
    int base = blockIdx.x * 1024 + tid * 4;
    int s = 0;
    if (base + 4 <= N_NODES) {
        int4 v = *(const int4*)(cnt + base);
        s = v.x + v.y + v.z + v.w;
    } else {
        for (int i = base; i < N_NODES && i < base + 4; i++) s += cnt[i];
    }
    sd[tid] = s;
    __syncthreads();
    for (int off = 128; off > 0; off >>= 1) {
        if (tid < off) sd[tid] += sd[tid + off];
        __syncthreads();
    }
    if (tid == 0) bsum[blockIdx.x] = sd[0];
}

// phase 2: scan the 98 block sums (in place -> exclusive), write rowptr[N]
__global__ __launch_bounds__(128) void scan_offsets(int* __restrict__ bsum, int* __restrict__ rowptr) {
    __shared__ int sd[128];
    int t = threadIdx.x;
    int v = (t < NB_SCAN) ? bsum[t] : 0;
    sd[t] = v;
    __syncthreads();
    for (int off = 1; off < 128; off <<= 1) {
        int u = (t >= off) ? sd[t - off] : 0;
        __syncthreads();
        sd[t] += u;
        __syncthreads();
    }
    if (t < NB_SCAN) bsum[t] = sd[t] - v;  // exclusive
    if (t == 0) rowptr[N_NODES] = N_EDGES;
}

// phase 3: per-block exclusive scan + block offset -> rowptr AND cursor copy
__global__ __launch_bounds__(256) void scan_final(const int* __restrict__ cnt,
                                                  const int* __restrict__ boff,
                                                  int* __restrict__ rowptr,
                                                  int* __restrict__ cursor) {
    __shared__ int sd[256];
    int tid = threadIdx.x;
    int base = blockIdx.x * 1024 + tid * 4;
    bool full = (base + 4 <= N_NODES);
    int4 v = make_int4(0, 0, 0, 0);
    if (full) {
        v = *(const int4*)(cnt + base);
    } else {
        if (base + 0 < N_NODES) v.x = cnt[base + 0];
        if (base + 1 < N_NODES) v.y = cnt[base + 1];
        if (base + 2 < N_NODES) v.z = cnt[base + 2];
        if (base + 3 < N_NODES) v.w = cnt[base + 3];
    }
    int s = v.x + v.y + v.z + v.w;
    sd[tid] = s;
    __syncthreads();
    for (int off = 1; off < 256; off <<= 1) {
        int u = (tid >= off) ? sd[tid - off] : 0;
        __syncthreads();
        sd[tid] += u;
        __syncthreads();
    }
    int pre = sd[tid] - s + boff[blockIdx.x];
    int4 w;
    w.x = pre;
    w.y = pre + v.x;
    w.z = pre + v.x + v.y;
    w.w = pre + v.x + v.y + v.z;
    if (full) {
        *(int4*)(rowptr + base) = w;
        *(int4*)(cursor + base) = w;
    } else {
        if (base + 0 < N_NODES) { rowptr[base + 0] = w.x; cursor[base + 0] = w.x; }
        if (base + 1 < N_NODES) { rowptr[base + 1] = w.y; cursor[base + 1] = w.y; }
        if (base + 2 < N_NODES) { rowptr[base + 2] = w.z; cursor[base + 2] = w.z; }
        if (base + 3 < N_NODES) { rowptr[base + 3] = w.w; cursor[base + 3] = w.w; }
    }
}

// scatter packed records {src, ea packed bf16x2} in CSR(dst) order; cursor pre-init to rowptr
#define SC_EPT 4  // edges per thread
__global__ __launch_bounds__(256) void scatter_kernel(const int* __restrict__ src,
                                                      const int* __restrict__ dst,
                                                      const float2* __restrict__ ea,
                                                      int* __restrict__ cursor,
                                                      uint2* __restrict__ recs) {
    int base = (blockIdx.x * 256 + threadIdx.x) * SC_EPT;
#pragma unroll
    for (int q = 0; q < SC_EPT; q++) {
        int e = base + q;
        if (e < N_EDGES) {
            int d = dst[e];
            int pos = atomicAdd(&cursor[d], 1);
            float2 a = ea[e];
            uint ap = (uint)f2bf(a.x) | ((uint)f2bf(a.y) << 16);
            recs[pos] = make_uint2((uint)src[e], ap);
        }
    }
}

// ---------------- GINE edge gather (one wave per node), bf16 features ----------------
// tb[n][:] = xb[n][:] + sum_e relu(xb[src_e][:] + ea0*We[0] + ea1*We[1] + be)

template <int VPL>
__device__ __forceinline__ void load_row(const ushort* __restrict__ xb, int s, int lane, float* x) {
    if constexpr (VPL == 1) {
        x[0] = bf2f(xb[(size_t)s * 64 + lane]);
    } else {
        uint u = *(const uint*)(xb + (size_t)s * 128 + lane * 2);
        x[0] = bf2f((ushort)(u & 0xFFFF));
        x[1] = bf2f((ushort)(u >> 16));
    }
}

template <int D>
__global__ __launch_bounds__(256) void gine_gather(const ushort* __restrict__ xb,
                                                   const uint2* __restrict__ recs,
                                                   const int* __restrict__ rowptr,
                                                   const float* __restrict__ We,
                                                   const float* __restrict__ be,
                                                   ushort* __restrict__ tb) {
    constexpr int VPL = D / 64;
    int node = (blockIdx.x * 256 + (int)threadIdx.x) >> 6;
    int lane = threadIdx.x & 63;
    if (node >= N_NODES) return;

    float w0[VPL], w1[VPL], bb[VPL], acc[VPL];
#pragma unroll
    for (int v = 0; v < VPL; v++) {
        int j = lane * VPL + v;
        w0[v] = We[j];
        w1[v] = We[D + j];
        bb[v] = be[j];
        acc[v] = 0.f;
    }

    int rs = rowptr[node];
    int re = rowptr[node + 1];

    int t = rs;
    for (; t + 3 < re; t += 4) {
        uint2 r0 = recs[t];
        uint2 r1 = recs[t + 1];
        uint2 r2 = recs[t + 2];
        uint2 r3 = recs[t + 3];
        float x0[VPL], x1[VPL], x2[VPL], x3[VPL];
        load_row<VPL>(xb, (int)r0.x, lane, x0);
        load_row<VPL>(xb, (int)r1.x, lane, x1);
        load_row<VPL>(xb, (int)r2.x, lane, x2);
        load_row<VPL>(xb, (int)r3.x, lane, x3);
        float a0x = bf2f((ushort)(r0.y & 0xFFFF)), a0y = bf2f((ushort)(r0.y >> 16));
        float a1x = bf2f((ushort)(r1.y & 0xFFFF)), a1y = bf2f((ushort)(r1.y >> 16));
        float a2x = bf2f((ushort)(r2.y & 0xFFFF)), a2y = bf2f((ushort)(r2.y >> 16));
        float a3x = bf2f((ushort)(r3.y & 0xFFFF)), a3y = bf2f((ushort)(r3.y >> 16));
#pragma unroll
        for (int v = 0; v < VPL; v++) {
            acc[v] += fmaxf(x0[v] + a0x * w0[v] + a0y * w1[v] + bb[v], 0.f);
            acc[v] += fmaxf(x1[v] + a1x * w0[v] + a1y * w1[v] + bb[v], 0.f);
            acc[v] += fmaxf(x2[v] + a2x * w0[v] + a2y * w1[v] + bb[v], 0.f);
            acc[v] += fmaxf(x3[v] + a3x * w0[v] + a3y * w1[v] + bb[v], 0.f);
        }
    }
    for (; t < re; t++) {
        uint2 rA = recs[t];
        float xA[VPL];
        load_row<VPL>(xb, (int)rA.x, lane, xA);
        float aAx = bf2f((ushort)(rA.y & 0xFFFF)), aAy = bf2f((ushort)(rA.y >> 16));
#pragma unroll
        for (int v = 0; v < VPL; v++) {
            acc[v] += fmaxf(xA[v] + aAx * w0[v] + aAy * w1[v] + bb[v], 0.f);
        }
    }

    // residual
    float xr[VPL];
    load_row<VPL>(xb, node, lane, xr);
#pragma unroll
    for (int v = 0; v < VPL; v++) acc[v] += xr[v];

    if constexpr (VPL == 1) {
        tb[(size_t)node * 64 + lane] = f2bf(acc[0]);
    } else {
        uint u = (uint)f2bf(acc[0]) | ((uint)f2bf(acc[1]) << 16);
        ((uint*)tb)[(size_t)node * 64 + lane] = u;
    }
}

// ---------------- node transform: hb = leaky(tb @ Wn + bn), bf16 in/out ----------------

template <int DIN, int NPB>
__global__ __launch_bounds__(128) void gine_transform(const ushort* __restrict__ tb,
                                                      const float* __restrict__ Wn,
                                                      const float* __restrict__ bn,
                                                      ushort* __restrict__ hb) {
    __shared__ float tt[NPB][DIN];
    int node0 = blockIdx.x * NPB;
    int j = threadIdx.x;  // output feature 0..127

    const uint* tsrc = (const uint*)(tb + (size_t)node0 * DIN);
    for (int idx = (int)threadIdx.x; idx < NPB * DIN / 2; idx += 128) {
        uint u = tsrc[idx];
        int base = idx * 2;
        tt[base / DIN][base % DIN] = bf2f((ushort)(u & 0xFFFF));
        tt[base / DIN][base % DIN + 1] = bf2f((ushort)(u >> 16));
    }
    __syncthreads();

    float acc[NPB];
#pragma unroll
    for (int m = 0; m < NPB; m++) acc[m] = bn[j];
    for (int k = 0; k < DIN; k += 4) {
        float wq0 = Wn[(k + 0) * HID + j];
        float wq1 = Wn[(k + 1) * HID + j];
        float wq2 = Wn[(k + 2) * HID + j];
        float wq3 = Wn[(k + 3) * HID + j];
#pragma unroll
        for (int m = 0; m < NPB; m++) {
            float4 tv = *(const float4*)&tt[m][k];
            acc[m] += tv.x * wq0 + tv.y * wq1 + tv.z * wq2 + tv.w * wq3;
        }
    }
#pragma unroll
    for (int m = 0; m < NPB; m++) {
        hb[(size_t)(node0 + m) * HID + j] = f2bf(leaky(acc[m]));
    }
}

// ---------------- pooling: batch is sorted; one block per graph ----------------

__global__ __launch_bounds__(128) void pool_kernel(const ushort* __restrict__ h,
                                                   const int* __restrict__ batch,
                                                   float* __restrict__ pooled) {
    int g = blockIdx.x;
    int lo = 0, hi = N_NODES;
    while (lo < hi) { int m = (lo + hi) >> 1; if (batch[m] < g) lo = m + 1; else hi = m; }
    int start = lo;
    lo = 0; hi = N_NODES;
    while (lo < hi) { int m = (lo + hi) >> 1; if (batch[m] < g + 1) lo = m + 1; else hi = m; }
    int end = lo;

    int j = threadIdx.x;
    float acc = 0.f;
    for (int i = start; i < end; i++) acc += bf2f(h[(size_t)i * HID + j]);
    pooled[g * HID + j] = acc;
}

// ---------------- head MLP ----------------

__global__ __launch_bounds__(256) void head_kernel(const float* __restrict__ pooled,
                                                   const float* __restrict__ Wh0,
                                                   const float* __restrict__ bh0,
                                                   const float* __restrict__ Wh1,
                                                   const float* __restrict__ bh1,
                                                   float* __restrict__ out) {
    __shared__ float p[HID];
    __shared__ float hid[HEAD_H];
    int g = blockIdx.x;
    int t = threadIdx.x;
    if (t < HID) p[t] = pooled[g * HID + t];
    __syncthreads();
    float acc = bh0[t];
    for (int k = 0; k < HID; k++) acc += p[k] * Wh0[k * HEAD_H + t];
    hid[t] = leaky(acc);
    __syncthreads();
    if (t < OUT_F) {
        float o = bh1[t];
        for (int k = 0; k < HEAD_H; k++) o += hid[k] * Wh1[k * OUT_F + t];
        out[g * OUT_F + t] = o;
    }
}

extern "C" void kernel_launch(void* const* d_in, const int* in_sizes, int n_in,
                              void* d_out, int out_size, void* d_ws, size_t ws_size,
                              hipStream_t stream) {
    const float* x     = (const float*)d_in[0];
    const int*   ei    = (const int*)d_in[1];
    const float* ea    = (const float*)d_in[2];
    const int*   batch = (const int*)d_in[3];
    const float* We0 = (const float*)d_in[4];
    const float* be0 = (const float*)d_in[5];
    const float* Wn0 = (const float*)d_in[6];
    const float* bn0 = (const float*)d_in[7];
    const float* We1 = (const float*)d_in[8];
    const float* be1 = (const float*)d_in[9];
    const float* Wn1 = (const float*)d_in[10];
    const float* bn1 = (const float*)d_in[11];
    const float* We2 = (const float*)d_in[12];
    const float* be2 = (const float*)d_in[13];
    const float* Wn2 = (const float*)d_in[14];
    const float* bn2 = (const float*)d_in[15];
    const float* Wh0 = (const float*)d_in[16];
    const float* bh0 = (const float*)d_in[17];
    const float* Wh1 = (const float*)d_in[18];
    const float* bh1 = (const float*)d_in[19];

    const int* src = ei;
    const int* dst = ei + N_EDGES;

    char* ws = (char*)d_ws;
    size_t o = 0;
    uint2*  recs = (uint2*)(ws + o);  o += (size_t)N_EDGES * 8;           // 12.8 MB
    ushort* xb0  = (ushort*)(ws + o); o += (size_t)N_NODES * 64 * 2;      // 12.8 MB
    ushort* tbuf = (ushort*)(ws + o); o += (size_t)N_NODES * 128 * 2;     // 25.6 MB
    ushort* hbuf = (ushort*)(ws + o); o += (size_t)N_NODES * 128 * 2;     // 25.6 MB
    int*    rowptr = (int*)(ws + o);  o += 400128;
    int*    cnt    = (int*)(ws + o);  o += 400128;
    int*    cursor = (int*)(ws + o);  o += 400128;
    int*    bsum   = (int*)(ws + o);  o += 4096;
    float*  pooled = (float*)(ws + o);

    // --- cast x to bf16 ---
    cast_kernel<<<(N_NODES * F_IN / 2 + 255) / 256, 256, 0, stream>>>(x, xb0, N_NODES * F_IN / 2);

    // --- CSR build (by dst) ---
    hipMemsetAsync(cnt, 0, N_NODES * sizeof(int), stream);
    hist_kernel<<<N_EDGES / 256, 256, 0, stream>>>(dst, cnt);
    scan_sums<<<NB_SCAN, 256, 0, stream>>>(cnt, bsum);
    scan_offsets<<<1, 128, 0, stream>>>(bsum, rowptr);
    scan_final<<<NB_SCAN, 256, 0, stream>>>(cnt, bsum, rowptr, cursor);
    scatter_kernel<<<(N_EDGES / SC_EPT + 255) / 256, 256, 0, stream>>>(src, dst, (const float2*)ea, cursor, recs);

    const int GATHER_BLOCKS = (N_NODES * 64 + 255) / 256;   // 25000
    const int TRANS_BLOCKS  = N_NODES / 8;                  // 12500

    // --- layer 0 (64 -> 128) ---
    gine_gather<64><<<GATHER_BLOCKS, 256, 0, stream>>>(xb0, recs, rowptr, We0, be0, tbuf);
    gine_transform<64, 8><<<TRANS_BLOCKS, 128, 0, stream>>>(tbuf, Wn0, bn0, hbuf);

    // --- layer 1 (128 -> 128) ---
    gine_gather<128><<<GATHER_BLOCKS, 256, 0, stream>>>(hbuf, recs, rowptr, We1, be1, tbuf);
    gine_transform<128, 8><<<TRANS_BLOCKS, 128, 0, stream>>>(tbuf, Wn1, bn1, hbuf);

    // --- layer 2 (128 -> 128) ---
    gine_gather<128><<<GATHER_BLOCKS, 256, 0, stream>>>(hbuf, recs, rowptr, We2, be2, tbuf);
    gine_transform<128, 8><<<TRANS_BLOCKS, 128, 0, stream>>>(tbuf, Wn2, bn2, hbuf);

    // --- pool + head ---
    pool_kernel<<<N_GRAPHS, 128, 0, stream>>>(hbuf, batch, pooled);
    head_kernel<<<N_GRAPHS, 256, 0, stream>>>(pooled, Wh0, bh0, Wh1, bh1, (float*)d_out);
}

// Round 5
// 527.182 us; speedup vs baseline: 2.5447x; 1.2579x over previous
//
#include <hip/hip_runtime.h>
#include <hip/hip_bf16.h>

#define N_NODES 100000
#define N_EDGES 1600000
#define F_IN 64
#define HID 128
#define HEAD_H 256
#define OUT_F 32
#define N_GRAPHS 512
#define NB_SCAN 98  // ceil(N_NODES / 1024)

typedef float f2v __attribute__((ext_vector_type(2)));
typedef short bf16x8 __attribute__((ext_vector_type(8)));
typedef float f32x4 __attribute__((ext_vector_type(4)));

__device__ __forceinline__ float leaky(float v) {
    return v >= 0.f ? v : 0.01f * v;
}

__device__ __forceinline__ float bf2f(ushort u) {
    union { uint i; float f; } c; c.i = ((uint)u) << 16; return c.f;
}

__device__ __forceinline__ ushort f2bf(float f) {
    union { float f; uint i; } c; c.f = f;
    uint r = c.i + 0x7FFF + ((c.i >> 16) & 1);
    return (ushort)(r >> 16);
}

// ---------------- cast x -> bf16 ----------------
__global__ __launch_bounds__(256) void cast_kernel(const float* __restrict__ x,
                                                   ushort* __restrict__ xb, int n2) {
    int i = blockIdx.x * 256 + threadIdx.x;  // handles 2 elems
    if (i < n2) {
        float2 v = ((const float2*)x)[i];
        uint u = (uint)f2bf(v.x) | ((uint)f2bf(v.y) << 16);
        ((uint*)xb)[i] = u;
    }
}

// ---------------- weight prep: WnT[j][k] = bf16(Wn[k][j]) for 3 layers ----------------
__global__ __launch_bounds__(256) void prep_wnT(const float* __restrict__ Wn0,
                                                const float* __restrict__ Wn1,
                                                const float* __restrict__ Wn2,
                                                ushort* __restrict__ w0T,
                                                ushort* __restrict__ w1T,
                                                ushort* __restrict__ w2T) {
    int id = blockIdx.x * 256 + threadIdx.x;
    if (id < 128 * 64) {
        int j = id / 64, k = id % 64;
        w0T[id] = f2bf(Wn0[k * 128 + j]);
    } else if (id < 128 * 64 + 128 * 128) {
        int t = id - 128 * 64; int j = t / 128, k = t % 128;
        w1T[t] = f2bf(Wn1[k * 128 + j]);
    } else if (id < 128 * 64 + 2 * 128 * 128) {
        int t = id - 128 * 64 - 128 * 128; int j = t / 128, k = t % 128;
        w2T[t] = f2bf(Wn2[k * 128 + j]);
    }
}

// ---------------- CSR build ----------------

__global__ __launch_bounds__(256) void hist_kernel(const int* __restrict__ dst, int* __restrict__ cnt) {
    int e = blockIdx.x * 256 + threadIdx.x;
    if (e < N_EDGES) atomicAdd(&cnt[dst[e]], 1);
}

// phase 1: per-block (1024 elems) sums
__global__ __launch_bounds__(256) void scan_sums(const int* __restrict__ cnt, int* __restrict__ bsum) {
    __shared__ int sd[256];
    int tid = threadIdx.x;
    int base = blockIdx.x * 1024 + tid * 4;
    int s = 0;
    if (base + 4 <= N_NODES) {
        int4 v = *(const int4*)(cnt + base);
        s = v.x + v.y + v.z + v.w;
    } else {
        for (int i = base; i < N_NODES && i < base + 4; i++) s += cnt[i];
    }
    sd[tid] = s;
    __syncthreads();
    for (int off = 128; off > 0; off >>= 1) {
        if (tid < off) sd[tid] += sd[tid + off];
        __syncthreads();
    }
    if (tid == 0) bsum[blockIdx.x] = sd[0];
}

// phase 2: scan the 98 block sums (in place -> exclusive), write rowptr[N]
__global__ __launch_bounds__(128) void scan_offsets(int* __restrict__ bsum, int* __restrict__ rowptr) {
    __shared__ int sd[128];
    int t = threadIdx.x;
    int v = (t < NB_SCAN) ? bsum[t] : 0;
    sd[t] = v;
    __syncthreads();
    for (int off = 1; off < 128; off <<= 1) {
        int u = (t >= off) ? sd[t - off] : 0;
        __syncthreads();
        sd[t] += u;
        __syncthreads();
    }
    if (t < NB_SCAN) bsum[t] = sd[t] - v;  // exclusive
    if (t == 0) rowptr[N_NODES] = N_EDGES;
}

// phase 3: per-block exclusive scan + block offset -> rowptr AND cursor copy
__global__ __launch_bounds__(256) void scan_final(const int* __restrict__ cnt,
                                                  const int* __restrict__ boff,
                                                  int* __restrict__ rowptr,
                                                  int* __restrict__ cursor) {
    __shared__ int sd[256];
    int tid = threadIdx.x;
    int base = blockIdx.x * 1024 + tid * 4;
    bool full = (base + 4 <= N_NODES);
    int4 v = make_int4(0, 0, 0, 0);
    if (full) {
        v = *(const int4*)(cnt + base);
    } else {
        if (base + 0 < N_NODES) v.x = cnt[base + 0];
        if (base + 1 < N_NODES) v.y = cnt[base + 1];
        if (base + 2 < N_NODES) v.z = cnt[base + 2];
        if (base + 3 < N_NODES) v.w = cnt[base + 3];
    }
    int s = v.x + v.y + v.z + v.w;
    sd[tid] = s;
    __syncthreads();
    for (int off = 1; off < 256; off <<= 1) {
        int u = (tid >= off) ? sd[tid - off] : 0;
        __syncthreads();
        sd[tid] += u;
        __syncthreads();
    }
    int pre = sd[tid] - s + boff[blockIdx.x];
    int4 w;
    w.x = pre;
    w.y = pre + v.x;
    w.z = pre + v.x + v.y;
    w.w = pre + v.x + v.y + v.z;
    if (full) {
        *(int4*)(rowptr + base) = w;
        *(int4*)(cursor + base) = w;
    } else {
        if (base + 0 < N_NODES) { rowptr[base + 0] = w.x; cursor[base + 0] = w.x; }
        if (base + 1 < N_NODES) { rowptr[base + 1] = w.y; cursor[base + 1] = w.y; }
        if (base + 2 < N_NODES) { rowptr[base + 2] = w.z; cursor[base + 2] = w.z; }
        if (base + 3 < N_NODES) { rowptr[base + 3] = w.w; cursor[base + 3] = w.w; }
    }
}

// scatter packed records {src, ea packed bf16x2} in CSR(dst) order; cursor pre-init to rowptr
#define SC_EPT 4  // edges per thread
__global__ __launch_bounds__(256) void scatter_kernel(const int* __restrict__ src,
                                                      const int* __restrict__ dst,
                                                      const float2* __restrict__ ea,
                                                      int* __restrict__ cursor,
                                                      uint2* __restrict__ recs) {
    int base = (blockIdx.x * 256 + threadIdx.x) * SC_EPT;
#pragma unroll
    for (int q = 0; q < SC_EPT; q++) {
        int e = base + q;
        if (e < N_EDGES) {
            int d = dst[e];
            int pos = atomicAdd(&cursor[d], 1);
            float2 a = ea[e];
            uint ap = (uint)f2bf(a.x) | ((uint)f2bf(a.y) << 16);
            recs[pos] = make_uint2((uint)src[e], ap);
        }
    }
}

// ---------------- GINE edge gather (one wave per node), bf16 features ----------------
// tb[n][:] = xb[n][:] + sum_e relu(xb[src_e][:] + ea0*We[0] + ea1*We[1] + be)
// rs/re readfirstlane'd -> record loads scalarize (s_load), row loads use SGPR base.

template <int D>
__global__ __launch_bounds__(256) void gine_gather(const ushort* __restrict__ xb,
                                                   const uint2* __restrict__ recs,
                                                   const int* __restrict__ rowptr,
                                                   const float* __restrict__ We,
                                                   const float* __restrict__ be,
                                                   ushort* __restrict__ tb) {
    int node = (blockIdx.x * 256 + (int)threadIdx.x) >> 6;
    int lane = threadIdx.x & 63;
    if (node >= N_NODES) return;

    int rs = __builtin_amdgcn_readfirstlane(rowptr[node]);
    int re = __builtin_amdgcn_readfirstlane(rowptr[node + 1]);

    if constexpr (D == 128) {
        int j = lane * 2;
        f2v w0v = {We[j], We[j + 1]};
        f2v w1v = {We[128 + j], We[128 + j + 1]};
        f2v bbv = {be[j], be[j + 1]};
        f2v accv = {0.f, 0.f};
        const f2v zero = {0.f, 0.f};

        auto proc = [&](uint2 r, uint u) {
            float ax = bf2f((ushort)(r.y & 0xFFFF));
            float ay = bf2f((ushort)(r.y >> 16));
            union { uint i; float f; } lo, hi;
            lo.i = u << 16;
            hi.i = u & 0xFFFF0000u;
            f2v xv = {lo.f, hi.f};
            f2v m = xv + bbv;
            m = ay * w1v + m;
            m = ax * w0v + m;
            m = __builtin_elementwise_max(m, zero);
            accv += m;
        };

        int t = rs;
        for (; t + 3 < re; t += 4) {
            uint2 r0 = recs[t];
            uint2 r1 = recs[t + 1];
            uint2 r2 = recs[t + 2];
            uint2 r3 = recs[t + 3];
            uint u0 = *(const uint*)(xb + (size_t)r0.x * 128 + j);
            uint u1 = *(const uint*)(xb + (size_t)r1.x * 128 + j);
            uint u2 = *(const uint*)(xb + (size_t)r2.x * 128 + j);
            uint u3 = *(const uint*)(xb + (size_t)r3.x * 128 + j);
            proc(r0, u0); proc(r1, u1); proc(r2, u2); proc(r3, u3);
        }
        for (; t < re; t++) {
            uint2 r0 = recs[t];
            uint u0 = *(const uint*)(xb + (size_t)r0.x * 128 + j);
            proc(r0, u0);
        }

        // residual
        {
            uint u = *(const uint*)(xb + (size_t)node * 128 + j);
            union { uint i; float f; } lo, hi;
            lo.i = u << 16;
            hi.i = u & 0xFFFF0000u;
            f2v xv = {lo.f, hi.f};
            accv += xv;
        }
        uint up = (uint)f2bf(accv.x) | ((uint)f2bf(accv.y) << 16);
        ((uint*)tb)[(size_t)node * 64 + lane] = up;
    } else {
        float w0 = We[lane], w1 = We[64 + lane], bb = be[lane];
        float acc = 0.f;

        auto proc = [&](uint2 r, ushort u) {
            float ax = bf2f((ushort)(r.y & 0xFFFF));
            float ay = bf2f((ushort)(r.y >> 16));
            float m = bf2f(u) + bb;
            m = ay * w1 + m;
            m = ax * w0 + m;
            acc += fmaxf(m, 0.f);
        };

        int t = rs;
        for (; t + 3 < re; t += 4) {
            uint2 r0 = recs[t];
            uint2 r1 = recs[t + 1];
            uint2 r2 = recs[t + 2];
            uint2 r3 = recs[t + 3];
            ushort u0 = xb[(size_t)r0.x * 64 + lane];
            ushort u1 = xb[(size_t)r1.x * 64 + lane];
            ushort u2 = xb[(size_t)r2.x * 64 + lane];
            ushort u3 = xb[(size_t)r3.x * 64 + lane];
            proc(r0, u0); proc(r1, u1); proc(r2, u2); proc(r3, u3);
        }
        for (; t < re; t++) {
            uint2 r0 = recs[t];
            ushort u0 = xb[(size_t)r0.x * 64 + lane];
            proc(r0, u0);
        }
        acc += bf2f(xb[(size_t)node * 64 + lane]);
        tb[(size_t)node * 64 + lane] = f2bf(acc);
    }
}

// ---------------- node transform via MFMA: hb = leaky(tb @ Wn + bn), bf16 ----------------
// A-frag: row = lane&15, k = (lane>>4)*8 + e   (16B contiguous from tb)
// B-frag: col = lane&15, k = (lane>>4)*8 + e   (16B contiguous from WnT[j][k])
// C/D   : col = lane&15, row = (lane>>4)*4 + reg   [m89-verified]

template <int K>
__global__ __launch_bounds__(256) void gine_transform_mfma(const ushort* __restrict__ tb,
                                                           const ushort* __restrict__ wnT,
                                                           const float* __restrict__ bn,
                                                           ushort* __restrict__ hb) {
    int wave = threadIdx.x >> 6;
    int lane = threadIdx.x & 63;
    int m0 = blockIdx.x * 64 + wave * 16;
    int l15 = lane & 15;
    int kgrp = (lane >> 4) * 8;

    const ushort* aptr = tb + (size_t)(m0 + l15) * K + kgrp;

    f32x4 acc[8];
#pragma unroll
    for (int nt = 0; nt < 8; nt++) {
        float b = bn[nt * 16 + l15];
        acc[nt] = {b, b, b, b};
    }

#pragma unroll
    for (int kk = 0; kk < K / 32; kk++) {
        bf16x8 a = *(const bf16x8*)(aptr + kk * 32);
#pragma unroll
        for (int nt = 0; nt < 8; nt++) {
            bf16x8 bfrag = *(const bf16x8*)(wnT + (size_t)(nt * 16 + l15) * K + kk * 32 + kgrp);
            acc[nt] = __builtin_amdgcn_mfma_f32_16x16x32_bf16(a, bfrag, acc[nt], 0, 0, 0);
        }
    }

    int rbase = m0 + (lane >> 4) * 4;
#pragma unroll
    for (int nt = 0; nt < 8; nt++) {
#pragma unroll
        for (int r = 0; r < 4; r++) {
            int nd = rbase + r;
            if (nd < N_NODES)
                hb[(size_t)nd * HID + nt * 16 + l15] = f2bf(leaky(acc[nt][r]));
        }
    }
}

// ---------------- pooling: batch is sorted; one block per graph ----------------

__global__ __launch_bounds__(128) void pool_kernel(const ushort* __restrict__ h,
                                                   const int* __restrict__ batch,
                                                   float* __restrict__ pooled) {
    int g = blockIdx.x;
    int lo = 0, hi = N_NODES;
    while (lo < hi) { int m = (lo + hi) >> 1; if (batch[m] < g) lo = m + 1; else hi = m; }
    int start = lo;
    lo = 0; hi = N_NODES;
    while (lo < hi) { int m = (lo + hi) >> 1; if (batch[m] < g + 1) lo = m + 1; else hi = m; }
    int end = lo;

    int j = threadIdx.x;
    float acc = 0.f;
    for (int i = start; i < end; i++) acc += bf2f(h[(size_t)i * HID + j]);
    pooled[g * HID + j] = acc;
}

// ---------------- head MLP ----------------

__global__ __launch_bounds__(256) void head_kernel(const float* __restrict__ pooled,
                                                   const float* __restrict__ Wh0,
                                                   const float* __restrict__ bh0,
                                                   const float* __restrict__ Wh1,
                                                   const float* __restrict__ bh1,
                                                   float* __restrict__ out) {
    __shared__ float p[HID];
    __shared__ float hid[HEAD_H];
    int g = blockIdx.x;
    int t = threadIdx.x;
    if (t < HID) p[t] = pooled[g * HID + t];
    __syncthreads();
    float acc = bh0[t];
    for (int k = 0; k < HID; k++) acc += p[k] * Wh0[k * HEAD_H + t];
    hid[t] = leaky(acc);
    __syncthreads();
    if (t < OUT_F) {
        float o = bh1[t];
        for (int k = 0; k < HEAD_H; k++) o += hid[k] * Wh1[k * OUT_F + t];
        out[g * OUT_F + t] = o;
    }
}

extern "C" void kernel_launch(void* const* d_in, const int* in_sizes, int n_in,
                              void* d_out, int out_size, void* d_ws, size_t ws_size,
                              hipStream_t stream) {
    const float* x     = (const float*)d_in[0];
    const int*   ei    = (const int*)d_in[1];
    const float* ea    = (const float*)d_in[2];
    const int*   batch = (const int*)d_in[3];
    const float* We0 = (const float*)d_in[4];
    const float* be0 = (const float*)d_in[5];
    const float* Wn0 = (const float*)d_in[6];
    const float* bn0 = (const float*)d_in[7];
    const float* We1 = (const float*)d_in[8];
    const float* be1 = (const float*)d_in[9];
    const float* Wn1 = (const float*)d_in[10];
    const float* bn1 = (const float*)d_in[11];
    const float* We2 = (const float*)d_in[12];
    const float* be2 = (const float*)d_in[13];
    const float* Wn2 = (const float*)d_in[14];
    const float* bn2 = (const float*)d_in[15];
    const float* Wh0 = (const float*)d_in[16];
    const float* bh0 = (const float*)d_in[17];
    const float* Wh1 = (const float*)d_in[18];
    const float* bh1 = (const float*)d_in[19];

    const int* src = ei;
    const int* dst = ei + N_EDGES;

    char* ws = (char*)d_ws;
    size_t o = 0;
    uint2*  recs = (uint2*)(ws + o);  o += (size_t)N_EDGES * 8;           // 12.8 MB
    ushort* xb0  = (ushort*)(ws + o); o += (size_t)N_NODES * 64 * 2;      // 12.8 MB
    ushort* tbuf = (ushort*)(ws + o); o += (size_t)N_NODES * 128 * 2;     // 25.6 MB
    ushort* hbuf = (ushort*)(ws + o); o += (size_t)N_NODES * 128 * 2;     // 25.6 MB
    int*    rowptr = (int*)(ws + o);  o += 400128;
    int*    cnt    = (int*)(ws + o);  o += 400128;
    int*    cursor = (int*)(ws + o);  o += 400128;
    int*    bsum   = (int*)(ws + o);  o += 4096;
    ushort* wnT0 = (ushort*)(ws + o); o += 128 * 64 * 2;
    ushort* wnT1 = (ushort*)(ws + o); o += 128 * 128 * 2;
    ushort* wnT2 = (ushort*)(ws + o); o += 128 * 128 * 2;
    float*  pooled = (float*)(ws + o);

    // --- cast x to bf16; prep transposed bf16 weights ---
    cast_kernel<<<(N_NODES * F_IN / 2 + 255) / 256, 256, 0, stream>>>(x, xb0, N_NODES * F_IN / 2);
    prep_wnT<<<160, 256, 0, stream>>>(Wn0, Wn1, Wn2, wnT0, wnT1, wnT2);

    // --- CSR build (by dst) ---
    hipMemsetAsync(cnt, 0, N_NODES * sizeof(int), stream);
    hist_kernel<<<N_EDGES / 256, 256, 0, stream>>>(dst, cnt);
    scan_sums<<<NB_SCAN, 256, 0, stream>>>(cnt, bsum);
    scan_offsets<<<1, 128, 0, stream>>>(bsum, rowptr);
    scan_final<<<NB_SCAN, 256, 0, stream>>>(cnt, bsum, rowptr, cursor);
    scatter_kernel<<<(N_EDGES / SC_EPT + 255) / 256, 256, 0, stream>>>(src, dst, (const float2*)ea, cursor, recs);

    const int GATHER_BLOCKS = (N_NODES * 64 + 255) / 256;   // 25000
    const int TRANS_BLOCKS  = (N_NODES + 63) / 64;          // 1563

    // --- layer 0 (64 -> 128) ---
    gine_gather<64><<<GATHER_BLOCKS, 256, 0, stream>>>(xb0, recs, rowptr, We0, be0, tbuf);
    gine_transform_mfma<64><<<TRANS_BLOCKS, 256, 0, stream>>>(tbuf, wnT0, bn0, hbuf);

    // --- layer 1 (128 -> 128) ---
    gine_gather<128><<<GATHER_BLOCKS, 256, 0, stream>>>(hbuf, recs, rowptr, We1, be1, tbuf);
    gine_transform_mfma<128><<<TRANS_BLOCKS, 256, 0, stream>>>(tbuf, wnT1, bn1, hbuf);

    // --- layer 2 (128 -> 128) ---
    gine_gather<128><<<GATHER_BLOCKS, 256, 0, stream>>>(hbuf, recs, rowptr, We2, be2, tbuf);
    gine_transform_mfma<128><<<TRANS_BLOCKS, 256, 0, stream>>>(tbuf, wnT2, bn2, hbuf);

    // --- pool + head ---
    pool_kernel<<<N_GRAPHS, 128, 0, stream>>>(hbuf, batch, pooled);
    head_kernel<<<N_GRAPHS, 256, 0, stream>>>(pooled, Wh0, bh0, Wh1, bh1, (float*)d_out);
}

// Round 6
// 491.051 us; speedup vs baseline: 2.7319x; 1.0736x over previous
//
#include <hip/hip_runtime.h>
#include <hip/hip_bf16.h>

#define N_NODES 100000
#define N_EDGES 1600000
#define F_IN 64
#define HID 128
#define HEAD_H 256
#define OUT_F 32
#define N_GRAPHS 512
#define NB_SCAN 98   // ceil(N_NODES / 1024)
#define NBK 98       // coarse buckets (dst >> 10)
#define BCHUNK 4096  // edges per bin-kernel block
#define NCHUNKS ((N_EDGES + BCHUNK - 1) / BCHUNK)  // 391

typedef float f2v __attribute__((ext_vector_type(2)));
typedef short bf16x8 __attribute__((ext_vector_type(8)));
typedef float f32x4 __attribute__((ext_vector_type(4)));

__device__ __forceinline__ float leaky(float v) {
    return v >= 0.f ? v : 0.01f * v;
}

__device__ __forceinline__ float bf2f(ushort u) {
    union { uint i; float f; } c; c.i = ((uint)u) << 16; return c.f;
}

__device__ __forceinline__ ushort f2bf(float f) {
    union { float f; uint i; } c; c.f = f;
    uint r = c.i + 0x7FFF + ((c.i >> 16) & 1);
    return (ushort)(r >> 16);
}

// ---------------- cast x -> bf16 ----------------
__global__ __launch_bounds__(256) void cast_kernel(const float* __restrict__ x,
                                                   ushort* __restrict__ xb, int n2) {
    int i = blockIdx.x * 256 + threadIdx.x;  // handles 2 elems
    if (i < n2) {
        float2 v = ((const float2*)x)[i];
        uint u = (uint)f2bf(v.x) | ((uint)f2bf(v.y) << 16);
        ((uint*)xb)[i] = u;
    }
}

// ---------------- weight prep: WnT[j][k] = bf16(Wn[k][j]) for 3 layers ----------------
__global__ __launch_bounds__(256) void prep_wnT(const float* __restrict__ Wn0,
                                                const float* __restrict__ Wn1,
                                                const float* __restrict__ Wn2,
                                                ushort* __restrict__ w0T,
                                                ushort* __restrict__ w1T,
                                                ushort* __restrict__ w2T) {
    int id = blockIdx.x * 256 + threadIdx.x;
    if (id < 128 * 64) {
        int j = id / 64, k = id % 64;
        w0T[id] = f2bf(Wn0[k * 128 + j]);
    } else if (id < 128 * 64 + 128 * 128) {
        int t = id - 128 * 64; int j = t / 128, k = t % 128;
        w1T[t] = f2bf(Wn1[k * 128 + j]);
    } else if (id < 128 * 64 + 2 * 128 * 128) {
        int t = id - 128 * 64 - 128 * 128; int j = t / 128, k = t % 128;
        w2T[t] = f2bf(Wn2[k * 128 + j]);
    }
}

// ---------------- CSR build ----------------

__global__ __launch_bounds__(256) void hist_kernel(const int* __restrict__ dst, int* __restrict__ cnt) {
    int e = blockIdx.x * 256 + threadIdx.x;
    if (e < N_EDGES) atomicAdd(&cnt[dst[e]], 1);
}

// phase 1: per-block (1024 elems) sums
__global__ __launch_bounds__(256) void scan_sums(const int* __restrict__ cnt, int* __restrict__ bsum) {
    __shared__ int sd[256];
    int tid = threadIdx.x;
    int base = blockIdx.x * 1024 + tid * 4;
    int s = 0;
    if (base + 4 <= N_NODES) {
        int4 v = *(const int4*)(cnt + base);
        s = v.x + v.y + v.z + v.w;
    } else {
        for (int i = base; i < N_NODES && i < base + 4; i++) s += cnt[i];
    }
    sd[tid] = s;
    __syncthreads();
    for (int off = 128; off > 0; off >>= 1) {
        if (tid < off) sd[tid] += sd[tid + off];
        __syncthreads();
    }
    if (tid == 0) bsum[blockIdx.x] = sd[0];
}

// phase 2: scan the 98 block sums (in place -> exclusive), write rowptr[N]
__global__ __launch_bounds__(128) void scan_offsets(int* __restrict__ bsum, int* __restrict__ rowptr) {
    __shared__ int sd[128];
    int t = threadIdx.x;
    int v = (t < NB_SCAN) ? bsum[t] : 0;
    sd[t] = v;
    __syncthreads();
    for (int off = 1; off < 128; off <<= 1) {
        int u = (t >= off) ? sd[t - off] : 0;
        __syncthreads();
        sd[t] += u;
        __syncthreads();
    }
    if (t < NB_SCAN) bsum[t] = sd[t] - v;  // exclusive
    if (t == 0) rowptr[N_NODES] = N_EDGES;
}

// phase 3: per-block exclusive scan + block offset -> rowptr
__global__ __launch_bounds__(256) void scan_final(const int* __restrict__ cnt,
                                                  const int* __restrict__ boff,
                                                  int* __restrict__ rowptr) {
    __shared__ int sd[256];
    int tid = threadIdx.x;
    int base = blockIdx.x * 1024 + tid * 4;
    bool full = (base + 4 <= N_NODES);
    int4 v = make_int4(0, 0, 0, 0);
    if (full) {
        v = *(const int4*)(cnt + base);
    } else {
        if (base + 0 < N_NODES) v.x = cnt[base + 0];
        if (base + 1 < N_NODES) v.y = cnt[base + 1];
        if (base + 2 < N_NODES) v.z = cnt[base + 2];
        if (base + 3 < N_NODES) v.w = cnt[base + 3];
    }
    int s = v.x + v.y + v.z + v.w;
    sd[tid] = s;
    __syncthreads();
    for (int off = 1; off < 256; off <<= 1) {
        int u = (tid >= off) ? sd[tid - off] : 0;
        __syncthreads();
        sd[tid] += u;
        __syncthreads();
    }
    int pre = sd[tid] - s + boff[blockIdx.x];
    int4 w;
    w.x = pre;
    w.y = pre + v.x;
    w.z = pre + v.x + v.y;
    w.w = pre + v.x + v.y + v.z;
    if (full) {
        *(int4*)(rowptr + base) = w;
    } else {
        if (base + 0 < N_NODES) rowptr[base + 0] = w.x;
        if (base + 1 < N_NODES) rowptr[base + 1] = w.y;
        if (base + 2 < N_NODES) rowptr[base + 2] = w.z;
        if (base + 3 < N_NODES) rowptr[base + 3] = w.w;
    }
}

// bucket cursors: bcur[b] = rowptr[b<<10]
__global__ __launch_bounds__(128) void init_bcur(const int* __restrict__ rowptr, int* __restrict__ bcur) {
    int t = threadIdx.x;
    if (t < 128) {
        int n = t << 10;
        bcur[t] = rowptr[n > N_NODES ? N_NODES : n];
    }
}

// ---------------- pass 1: bin edges by dst>>10 into bucket regions of recs1 ----------------
// record: x = src | (dloc<<22), y = packed bf16 edge attrs. Order within bucket arbitrary.
__global__ __launch_bounds__(256) void bin_kernel(const int* __restrict__ src,
                                                  const int* __restrict__ dst,
                                                  const float2* __restrict__ ea,
                                                  int* __restrict__ bcur,
                                                  uint2* __restrict__ recs1) {
    __shared__ int hist[NBK], tmp[NBK], offs[NBK], cur[NBK], gbase[NBK];
    __shared__ uint2 stage[BCHUNK];
    __shared__ unsigned char sbid[BCHUNK];

    int tid = threadIdx.x;
    int e0 = blockIdx.x * BCHUNK;
    int nn = N_EDGES - e0; if (nn > BCHUNK) nn = BCHUNK;

    if (tid < NBK) hist[tid] = 0;
    __syncthreads();

    // phase A: histogram over this chunk
    for (int i = tid; i < nn; i += 256) {
        atomicAdd(&hist[dst[e0 + i] >> 10], 1);
    }
    __syncthreads();

    // scan hist -> offs (exclusive), Hillis-Steele over NBK entries
    if (tid < NBK) tmp[tid] = hist[tid];
    __syncthreads();
    for (int off = 1; off < NBK; off <<= 1) {
        int u = (tid < NBK && tid >= off) ? tmp[tid - off] : 0;
        __syncthreads();
        if (tid < NBK) tmp[tid] += u;
        __syncthreads();
    }
    if (tid < NBK) {
        int ex = tmp[tid] - hist[tid];
        offs[tid] = ex;
        cur[tid] = ex;
        gbase[tid] = (hist[tid] > 0) ? atomicAdd(&bcur[tid], hist[tid]) : 0;
    }
    __syncthreads();

    // phase B: place records into LDS, bucket-sorted
    for (int i = tid; i < nn; i += 256) {
        int e = e0 + i;
        int d = dst[e];
        int b = d >> 10;
        int dloc = d & 1023;
        float2 a = ea[e];
        uint2 r;
        r.x = (uint)src[e] | ((uint)dloc << 22);
        r.y = (uint)f2bf(a.x) | ((uint)f2bf(a.y) << 16);
        int pos = atomicAdd(&cur[b], 1);
        stage[pos] = r;
        sbid[pos] = (unsigned char)b;
    }
    __syncthreads();

    // phase C: flush contiguous per-bucket runs
    for (int i = tid; i < nn; i += 256) {
        int b = sbid[i];
        recs1[gbase[b] + (i - offs[b])] = stage[i];
    }
}

// ---------------- pass 2: order records within bucket into exact CSR slots ----------------
__global__ __launch_bounds__(256) void order_kernel(const uint2* __restrict__ recs1,
                                                    const int* __restrict__ rowptr,
                                                    uint2* __restrict__ recs2) {
    __shared__ int cur[1024];
    int b = blockIdx.x;
    int n0 = b << 10;
    int n1 = n0 + 1024; if (n1 > N_NODES) n1 = N_NODES;
    for (int i = threadIdx.x; i < 1024; i += 256) {
        int n = n0 + i;
        cur[i] = rowptr[n > N_NODES ? N_NODES : n];
    }
    __syncthreads();
    int base = rowptr[n0];
    int end = rowptr[n1];
    for (int t = base + (int)threadIdx.x; t < end; t += 256) {
        uint2 r = recs1[t];
        int dloc = r.x >> 22;
        int pos = atomicAdd(&cur[dloc], 1);
        recs2[pos] = make_uint2(r.x & 0x3FFFFFu, r.y);
    }
}

// ---------------- GINE edge gather (one wave per node), bf16 features ----------------

template <int D>
__global__ __launch_bounds__(256) void gine_gather(const ushort* __restrict__ xb,
                                                   const uint2* __restrict__ recs,
                                                   const int* __restrict__ rowptr,
                                                   const float* __restrict__ We,
                                                   const float* __restrict__ be,
                                                   ushort* __restrict__ tb) {
    int node = (blockIdx.x * 256 + (int)threadIdx.x) >> 6;
    int lane = threadIdx.x & 63;
    if (node >= N_NODES) return;

    int rs = __builtin_amdgcn_readfirstlane(rowptr[node]);
    int re = __builtin_amdgcn_readfirstlane(rowptr[node + 1]);

    if constexpr (D == 128) {
        int j = lane * 2;
        f2v w0v = {We[j], We[j + 1]};
        f2v w1v = {We[128 + j], We[128 + j + 1]};
        f2v bbv = {be[j], be[j + 1]};
        f2v accv = {0.f, 0.f};
        const f2v zero = {0.f, 0.f};

        auto proc = [&](uint2 r, uint u) {
            float ax = bf2f((ushort)(r.y & 0xFFFF));
            float ay = bf2f((ushort)(r.y >> 16));
            union { uint i; float f; } lo, hi;
            lo.i = u << 16;
            hi.i = u & 0xFFFF0000u;
            f2v xv = {lo.f, hi.f};
            f2v m = xv + bbv;
            m = ay * w1v + m;
            m = ax * w0v + m;
            m = __builtin_elementwise_max(m, zero);
            accv += m;
        };

        int t = rs;
        for (; t + 3 < re; t += 4) {
            uint2 r0 = recs[t];
            uint2 r1 = recs[t + 1];
            uint2 r2 = recs[t + 2];
            uint2 r3 = recs[t + 3];
            uint u0 = *(const uint*)(xb + (size_t)r0.x * 128 + j);
            uint u1 = *(const uint*)(xb + (size_t)r1.x * 128 + j);
            uint u2 = *(const uint*)(xb + (size_t)r2.x * 128 + j);
            uint u3 = *(const uint*)(xb + (size_t)r3.x * 128 + j);
            proc(r0, u0); proc(r1, u1); proc(r2, u2); proc(r3, u3);
        }
        for (; t < re; t++) {
            uint2 r0 = recs[t];
            uint u0 = *(const uint*)(xb + (size_t)r0.x * 128 + j);
            proc(r0, u0);
        }

        // residual
        {
            uint u = *(const uint*)(xb + (size_t)node * 128 + j);
            union { uint i; float f; } lo, hi;
            lo.i = u << 16;
            hi.i = u & 0xFFFF0000u;
            f2v xv = {lo.f, hi.f};
            accv += xv;
        }
        uint up = (uint)f2bf(accv.x) | ((uint)f2bf(accv.y) << 16);
        ((uint*)tb)[(size_t)node * 64 + lane] = up;
    } else {
        float w0 = We[lane], w1 = We[64 + lane], bb = be[lane];
        float acc = 0.f;

        auto proc = [&](uint2 r, ushort u) {
            float ax = bf2f((ushort)(r.y & 0xFFFF));
            float ay = bf2f((ushort)(r.y >> 16));
            float m = bf2f(u) + bb;
            m = ay * w1 + m;
            m = ax * w0 + m;
            acc += fmaxf(m, 0.f);
        };

        int t = rs;
        for (; t + 3 < re; t += 4) {
            uint2 r0 = recs[t];
            uint2 r1 = recs[t + 1];
            uint2 r2 = recs[t + 2];
            uint2 r3 = recs[t + 3];
            ushort u0 = xb[(size_t)r0.x * 64 + lane];
            ushort u1 = xb[(size_t)r1.x * 64 + lane];
            ushort u2 = xb[(size_t)r2.x * 64 + lane];
            ushort u3 = xb[(size_t)r3.x * 64 + lane];
            proc(r0, u0); proc(r1, u1); proc(r2, u2); proc(r3, u3);
        }
        for (; t < re; t++) {
            uint2 r0 = recs[t];
            ushort u0 = xb[(size_t)r0.x * 64 + lane];
            proc(r0, u0);
        }
        acc += bf2f(xb[(size_t)node * 64 + lane]);
        tb[(size_t)node * 64 + lane] = f2bf(acc);
    }
}

// ---------------- node transform via MFMA: hb = leaky(tb @ Wn + bn), bf16 ----------------

template <int K>
__global__ __launch_bounds__(256) void gine_transform_mfma(const ushort* __restrict__ tb,
                                                           const ushort* __restrict__ wnT,
                                                           const float* __restrict__ bn,
                                                           ushort* __restrict__ hb) {
    int wave = threadIdx.x >> 6;
    int lane = threadIdx.x & 63;
    int m0 = blockIdx.x * 64 + wave * 16;
    int l15 = lane & 15;
    int kgrp = (lane >> 4) * 8;

    const ushort* aptr = tb + (size_t)(m0 + l15) * K + kgrp;

    f32x4 acc[8];
#pragma unroll
    for (int nt = 0; nt < 8; nt++) {
        float b = bn[nt * 16 + l15];
        acc[nt] = {b, b, b, b};
    }

#pragma unroll
    for (int kk = 0; kk < K / 32; kk++) {
        bf16x8 a = *(const bf16x8*)(aptr + kk * 32);
#pragma unroll
        for (int nt = 0; nt < 8; nt++) {
            bf16x8 bfrag = *(const bf16x8*)(wnT + (size_t)(nt * 16 + l15) * K + kk * 32 + kgrp);
            acc[nt] = __builtin_amdgcn_mfma_f32_16x16x32_bf16(a, bfrag, acc[nt], 0, 0, 0);
        }
    }

    int rbase = m0 + (lane >> 4) * 4;
#pragma unroll
    for (int nt = 0; nt < 8; nt++) {
#pragma unroll
        for (int r = 0; r < 4; r++) {
            int nd = rbase + r;
            if (nd < N_NODES)
                hb[(size_t)nd * HID + nt * 16 + l15] = f2bf(leaky(acc[nt][r]));
        }
    }
}

// ---------------- pooling: batch is sorted; one block per graph ----------------

__global__ __launch_bounds__(128) void pool_kernel(const ushort* __restrict__ h,
                                                   const int* __restrict__ batch,
                                                   float* __restrict__ pooled) {
    int g = blockIdx.x;
    int lo = 0, hi = N_NODES;
    while (lo < hi) { int m = (lo + hi) >> 1; if (batch[m] < g) lo = m + 1; else hi = m; }
    int start = lo;
    lo = 0; hi = N_NODES;
    while (lo < hi) { int m = (lo + hi) >> 1; if (batch[m] < g + 1) lo = m + 1; else hi = m; }
    int end = lo;

    int j = threadIdx.x;
    float acc = 0.f;
    for (int i = start; i < end; i++) acc += bf2f(h[(size_t)i * HID + j]);
    pooled[g * HID + j] = acc;
}

// ---------------- head MLP ----------------

__global__ __launch_bounds__(256) void head_kernel(const float* __restrict__ pooled,
                                                   const float* __restrict__ Wh0,
                                                   const float* __restrict__ bh0,
                                                   const float* __restrict__ Wh1,
                                                   const float* __restrict__ bh1,
                                                   float* __restrict__ out) {
    __shared__ float p[HID];
    __shared__ float hid[HEAD_H];
    int g = blockIdx.x;
    int t = threadIdx.x;
    if (t < HID) p[t] = pooled[g * HID + t];
    __syncthreads();
    float acc = bh0[t];
    for (int k = 0; k < HID; k++) acc += p[k] * Wh0[k * HEAD_H + t];
    hid[t] = leaky(acc);
    __syncthreads();
    if (t < OUT_F) {
        float o = bh1[t];
        for (int k = 0; k < HEAD_H; k++) o += hid[k] * Wh1[k * OUT_F + t];
        out[g * OUT_F + t] = o;
    }
}

extern "C" void kernel_launch(void* const* d_in, const int* in_sizes, int n_in,
                              void* d_out, int out_size, void* d_ws, size_t ws_size,
                              hipStream_t stream) {
    const float* x     = (const float*)d_in[0];
    const int*   ei    = (const int*)d_in[1];
    const float* ea    = (const float*)d_in[2];
    const int*   batch = (const int*)d_in[3];
    const float* We0 = (const float*)d_in[4];
    const float* be0 = (const float*)d_in[5];
    const float* Wn0 = (const float*)d_in[6];
    const float* bn0 = (const float*)d_in[7];
    const float* We1 = (const float*)d_in[8];
    const float* be1 = (const float*)d_in[9];
    const float* Wn1 = (const float*)d_in[10];
    const float* bn1 = (const float*)d_in[11];
    const float* We2 = (const float*)d_in[12];
    const float* be2 = (const float*)d_in[13];
    const float* Wn2 = (const float*)d_in[14];
    const float* bn2 = (const float*)d_in[15];
    const float* Wh0 = (const float*)d_in[16];
    const float* bh0 = (const float*)d_in[17];
    const float* Wh1 = (const float*)d_in[18];
    const float* bh1 = (const float*)d_in[19];

    const int* src = ei;
    const int* dst = ei + N_EDGES;

    char* ws = (char*)d_ws;
    size_t o = 0;
    uint2*  recs1 = (uint2*)(ws + o); o += (size_t)N_EDGES * 8;           // 12.8 MB
    uint2*  recs2 = (uint2*)(ws + o); o += (size_t)N_EDGES * 8;           // 12.8 MB
    ushort* xb0  = (ushort*)(ws + o); o += (size_t)N_NODES * 64 * 2;      // 12.8 MB
    ushort* tbuf = (ushort*)(ws + o); o += (size_t)N_NODES * 128 * 2;     // 25.6 MB
    ushort* hbuf = (ushort*)(ws + o); o += (size_t)N_NODES * 128 * 2;     // 25.6 MB
    int*    rowptr = (int*)(ws + o);  o += 400128;
    int*    cnt    = (int*)(ws + o);  o += 400128;
    int*    bsum   = (int*)(ws + o);  o += 4096;
    int*    bcur   = (int*)(ws + o);  o += 4096;
    ushort* wnT0 = (ushort*)(ws + o); o += 128 * 64 * 2;
    ushort* wnT1 = (ushort*)(ws + o); o += 128 * 128 * 2;
    ushort* wnT2 = (ushort*)(ws + o); o += 128 * 128 * 2;
    float*  pooled = (float*)(ws + o);

    // --- cast x to bf16; prep transposed bf16 weights ---
    cast_kernel<<<(N_NODES * F_IN / 2 + 255) / 256, 256, 0, stream>>>(x, xb0, N_NODES * F_IN / 2);
    prep_wnT<<<160, 256, 0, stream>>>(Wn0, Wn1, Wn2, wnT0, wnT1, wnT2);

    // --- CSR build (by dst): hist -> rowptr -> two-phase bin/order sort ---
    hipMemsetAsync(cnt, 0, N_NODES * sizeof(int), stream);
    hist_kernel<<<N_EDGES / 256, 256, 0, stream>>>(dst, cnt);
    scan_sums<<<NB_SCAN, 256, 0, stream>>>(cnt, bsum);
    scan_offsets<<<1, 128, 0, stream>>>(bsum, rowptr);
    scan_final<<<NB_SCAN, 256, 0, stream>>>(cnt, bsum, rowptr);
    init_bcur<<<1, 128, 0, stream>>>(rowptr, bcur);
    bin_kernel<<<NCHUNKS, 256, 0, stream>>>(src, dst, (const float2*)ea, bcur, recs1);
    order_kernel<<<NBK, 256, 0, stream>>>(recs1, rowptr, recs2);

    const int GATHER_BLOCKS = (N_NODES * 64 + 255) / 256;   // 25000
    const int TRANS_BLOCKS  = (N_NODES + 63) / 64;          // 1563

    // --- layer 0 (64 -> 128) ---
    gine_gather<64><<<GATHER_BLOCKS, 256, 0, stream>>>(xb0, recs2, rowptr, We0, be0, tbuf);
    gine_transform_mfma<64><<<TRANS_BLOCKS, 256, 0, stream>>>(tbuf, wnT0, bn0, hbuf);

    // --- layer 1 (128 -> 128) ---
    gine_gather<128><<<GATHER_BLOCKS, 256, 0, stream>>>(hbuf, recs2, rowptr, We1, be1, tbuf);
    gine_transform_mfma<128><<<TRANS_BLOCKS, 256, 0, stream>>>(tbuf, wnT1, bn1, hbuf);

    // --- layer 2 (128 -> 128) ---
    gine_gather<128><<<GATHER_BLOCKS, 256, 0, stream>>>(hbuf, recs2, rowptr, We2, be2, tbuf);
    gine_transform_mfma<128><<<TRANS_BLOCKS, 256, 0, stream>>>(tbuf, wnT2, bn2, hbuf);

    // --- pool + head ---
    pool_kernel<<<N_GRAPHS, 128, 0, stream>>>(hbuf, batch, pooled);
    head_kernel<<<N_GRAPHS, 256, 0, stream>>>(pooled, Wh0, bh0, Wh1, bh1, (float*)d_out);
}

// Round 7
// 455.107 us; speedup vs baseline: 2.9477x; 1.0790x over previous
//
#include <hip/hip_runtime.h>
#include <hip/hip_bf16.h>

#define N_NODES 100000
#define N_EDGES 1600000
#define F_IN 64
#define HID 128
#define HEAD_H 256
#define OUT_F 32
#define N_GRAPHS 512
#define NB_SCAN 98   // ceil(N_NODES / 1024)
#define NBK 98       // coarse buckets (dst >> 10)
#define BCHUNK 4096  // edges per bin-kernel block
#define NCHUNKS ((N_EDGES + BCHUNK - 1) / BCHUNK)  // 391

typedef float f2v __attribute__((ext_vector_type(2)));
typedef short bf16x8 __attribute__((ext_vector_type(8)));
typedef float f32x4 __attribute__((ext_vector_type(4)));

__device__ __forceinline__ float leaky(float v) {
    return v >= 0.f ? v : 0.01f * v;
}

__device__ __forceinline__ float bf2f(ushort u) {
    union { uint i; float f; } c; c.i = ((uint)u) << 16; return c.f;
}

__device__ __forceinline__ ushort f2bf(float f) {
    union { float f; uint i; } c; c.f = f;
    uint r = c.i + 0x7FFF + ((c.i >> 16) & 1);
    return (ushort)(r >> 16);
}

// ---------------- cast x -> bf16 ----------------
__global__ __launch_bounds__(256) void cast_kernel(const float* __restrict__ x,
                                                   ushort* __restrict__ xb, int n2) {
    int i = blockIdx.x * 256 + threadIdx.x;  // handles 2 elems
    if (i < n2) {
        float2 v = ((const float2*)x)[i];
        uint u = (uint)f2bf(v.x) | ((uint)f2bf(v.y) << 16);
        ((uint*)xb)[i] = u;
    }
}

// ---------------- weight prep: WnT[j][k] = bf16(Wn[k][j]) for 3 layers ----------------
__global__ __launch_bounds__(256) void prep_wnT(const float* __restrict__ Wn0,
                                                const float* __restrict__ Wn1,
                                                const float* __restrict__ Wn2,
                                                ushort* __restrict__ w0T,
                                                ushort* __restrict__ w1T,
                                                ushort* __restrict__ w2T) {
    int id = blockIdx.x * 256 + threadIdx.x;
    if (id < 128 * 64) {
        int j = id / 64, k = id % 64;
        w0T[id] = f2bf(Wn0[k * 128 + j]);
    } else if (id < 128 * 64 + 128 * 128) {
        int t = id - 128 * 64; int j = t / 128, k = t % 128;
        w1T[t] = f2bf(Wn1[k * 128 + j]);
    } else if (id < 128 * 64 + 2 * 128 * 128) {
        int t = id - 128 * 64 - 128 * 128; int j = t / 128, k = t % 128;
        w2T[t] = f2bf(Wn2[k * 128 + j]);
    }
}

// ---------------- CSR build ----------------

__global__ __launch_bounds__(256) void hist_kernel(const int* __restrict__ dst, int* __restrict__ cnt) {
    int i = (blockIdx.x * 256 + threadIdx.x) * 4;
    if (i + 4 <= N_EDGES) {
        int4 v = *(const int4*)(dst + i);
        atomicAdd(&cnt[v.x], 1);
        atomicAdd(&cnt[v.y], 1);
        atomicAdd(&cnt[v.z], 1);
        atomicAdd(&cnt[v.w], 1);
    } else {
        for (int e = i; e < N_EDGES; e++) atomicAdd(&cnt[dst[e]], 1);
    }
}

// phase 1: per-block (1024 elems) sums
__global__ __launch_bounds__(256) void scan_sums(const int* __restrict__ cnt, int* __restrict__ bsum) {
    __shared__ int sd[256];
    int tid = threadIdx.x;
    int base = blockIdx.x * 1024 + tid * 4;
    int s = 0;
    if (base + 4 <= N_NODES) {
        int4 v = *(const int4*)(cnt + base);
        s = v.x + v.y + v.z + v.w;
    } else {
        for (int i = base; i < N_NODES && i < base + 4; i++) s += cnt[i];
    }
    sd[tid] = s;
    __syncthreads();
    for (int off = 128; off > 0; off >>= 1) {
        if (tid < off) sd[tid] += sd[tid + off];
        __syncthreads();
    }
    if (tid == 0) bsum[blockIdx.x] = sd[0];
}

// phase 2: scan the 98 block sums (in place -> exclusive), write rowptr[N]
__global__ __launch_bounds__(128) void scan_offsets(int* __restrict__ bsum, int* __restrict__ rowptr) {
    __shared__ int sd[128];
    int t = threadIdx.x;
    int v = (t < NB_SCAN) ? bsum[t] : 0;
    sd[t] = v;
    __syncthreads();
    for (int off = 1; off < 128; off <<= 1) {
        int u = (t >= off) ? sd[t - off] : 0;
        __syncthreads();
        sd[t] += u;
        __syncthreads();
    }
    if (t < NB_SCAN) bsum[t] = sd[t] - v;  // exclusive
    if (t == 0) rowptr[N_NODES] = N_EDGES;
}

// phase 3: per-block exclusive scan + block offset -> rowptr
__global__ __launch_bounds__(256) void scan_final(const int* __restrict__ cnt,
                                                  const int* __restrict__ boff,
                                                  int* __restrict__ rowptr) {
    __shared__ int sd[256];
    int tid = threadIdx.x;
    int base = blockIdx.x * 1024 + tid * 4;
    bool full = (base + 4 <= N_NODES);
    int4 v = make_int4(0, 0, 0, 0);
    if (full) {
        v = *(const int4*)(cnt + base);
    } else {
        if (base + 0 < N_NODES) v.x = cnt[base + 0];
        if (base + 1 < N_NODES) v.y = cnt[base + 1];
        if (base + 2 < N_NODES) v.z = cnt[base + 2];
        if (base + 3 < N_NODES) v.w = cnt[base + 3];
    }
    int s = v.x + v.y + v.z + v.w;
    sd[tid] = s;
    __syncthreads();
    for (int off = 1; off < 256; off <<= 1) {
        int u = (tid >= off) ? sd[tid - off] : 0;
        __syncthreads();
        sd[tid] += u;
        __syncthreads();
    }
    int pre = sd[tid] - s + boff[blockIdx.x];
    int4 w;
    w.x = pre;
    w.y = pre + v.x;
    w.z = pre + v.x + v.y;
    w.w = pre + v.x + v.y + v.z;
    if (full) {
        *(int4*)(rowptr + base) = w;
    } else {
        if (base + 0 < N_NODES) rowptr[base + 0] = w.x;
        if (base + 1 < N_NODES) rowptr[base + 1] = w.y;
        if (base + 2 < N_NODES) rowptr[base + 2] = w.z;
        if (base + 3 < N_NODES) rowptr[base + 3] = w.w;
    }
}

// bucket cursors: bcur[b] = rowptr[b<<10]
__global__ __launch_bounds__(128) void init_bcur(const int* __restrict__ rowptr, int* __restrict__ bcur) {
    int t = threadIdx.x;
    if (t < 128) {
        int n = t << 10;
        bcur[t] = rowptr[n > N_NODES ? N_NODES : n];
    }
}

// ---------------- pass 1: bin edges by dst>>10 into bucket regions of recs1 ----------------
// record: x = src | (dloc<<22), y = packed bf16 edge attrs. Order within bucket arbitrary.
__global__ __launch_bounds__(256) void bin_kernel(const int* __restrict__ src,
                                                  const int* __restrict__ dst,
                                                  const float2* __restrict__ ea,
                                                  int* __restrict__ bcur,
                                                  uint2* __restrict__ recs1) {
    __shared__ int hist[NBK], tmp[NBK], offs[NBK], cur[NBK], gbase[NBK];
    __shared__ uint2 stage[BCHUNK];
    __shared__ unsigned char sbid[BCHUNK];

    int tid = threadIdx.x;
    int e0 = blockIdx.x * BCHUNK;
    int nn = N_EDGES - e0; if (nn > BCHUNK) nn = BCHUNK;

    if (tid < NBK) hist[tid] = 0;
    __syncthreads();

    // phase A: histogram over this chunk
    for (int i = tid; i < nn; i += 256) {
        atomicAdd(&hist[dst[e0 + i] >> 10], 1);
    }
    __syncthreads();

    // scan hist -> offs (exclusive), Hillis-Steele over NBK entries
    if (tid < NBK) tmp[tid] = hist[tid];
    __syncthreads();
    for (int off = 1; off < NBK; off <<= 1) {
        int u = (tid < NBK && tid >= off) ? tmp[tid - off] : 0;
        __syncthreads();
        if (tid < NBK) tmp[tid] += u;
        __syncthreads();
    }
    if (tid < NBK) {
        int ex = tmp[tid] - hist[tid];
        offs[tid] = ex;
        cur[tid] = ex;
        gbase[tid] = (hist[tid] > 0) ? atomicAdd(&bcur[tid], hist[tid]) : 0;
    }
    __syncthreads();

    // phase B: place records into LDS, bucket-sorted
    for (int i = tid; i < nn; i += 256) {
        int e = e0 + i;
        int d = dst[e];
        int b = d >> 10;
        int dloc = d & 1023;
        float2 a = ea[e];
        uint2 r;
        r.x = (uint)src[e] | ((uint)dloc << 22);
        r.y = (uint)f2bf(a.x) | ((uint)f2bf(a.y) << 16);
        int pos = atomicAdd(&cur[b], 1);
        stage[pos] = r;
        sbid[pos] = (unsigned char)b;
    }
    __syncthreads();

    // phase C: flush contiguous per-bucket runs
    for (int i = tid; i < nn; i += 256) {
        int b = sbid[i];
        recs1[gbase[b] + (i - offs[b])] = stage[i];
    }
}

// ---------------- pass 2: order records within bucket into exact CSR slots ----------------
__global__ __launch_bounds__(256) void order_kernel(const uint2* __restrict__ recs1,
                                                    const int* __restrict__ rowptr,
                                                    uint2* __restrict__ recs2) {
    __shared__ int cur[1024];
    int b = blockIdx.x;
    int n0 = b << 10;
    int n1 = n0 + 1024; if (n1 > N_NODES) n1 = N_NODES;
    for (int i = threadIdx.x; i < 1024; i += 256) {
        int n = n0 + i;
        cur[i] = rowptr[n > N_NODES ? N_NODES : n];
    }
    __syncthreads();
    int base = rowptr[n0];
    int end = rowptr[n1];
    for (int t = base + (int)threadIdx.x; t < end; t += 256) {
        uint2 r = recs1[t];
        int dloc = r.x >> 22;
        int pos = atomicAdd(&cur[dloc], 1);
        recs2[pos] = make_uint2(r.x & 0x3FFFFFu, r.y);
    }
}

// ---------------- GINE edge gather (one wave per node), bf16 features ----------------

template <int D>
__global__ __launch_bounds__(256) void gine_gather(const ushort* __restrict__ xb,
                                                   const uint2* __restrict__ recs,
                                                   const int* __restrict__ rowptr,
                                                   const float* __restrict__ We,
                                                   const float* __restrict__ be,
                                                   ushort* __restrict__ tb) {
    int node = (blockIdx.x * 256 + (int)threadIdx.x) >> 6;
    int lane = threadIdx.x & 63;
    if (node >= N_NODES) return;

    int rs = __builtin_amdgcn_readfirstlane(rowptr[node]);
    int re = __builtin_amdgcn_readfirstlane(rowptr[node + 1]);

    if constexpr (D == 128) {
        int j = lane * 2;
        f2v w0v = {We[j], We[j + 1]};
        f2v w1v = {We[128 + j], We[128 + j + 1]};
        f2v bbv = {be[j], be[j + 1]};
        f2v accv = {0.f, 0.f};
        const f2v zero = {0.f, 0.f};

        auto proc = [&](uint2 r, uint u) {
            float ax = bf2f((ushort)(r.y & 0xFFFF));
            float ay = bf2f((ushort)(r.y >> 16));
            union { uint i; float f; } lo, hi;
            lo.i = u << 16;
            hi.i = u & 0xFFFF0000u;
            f2v xv = {lo.f, hi.f};
            f2v m = xv + bbv;
            m = ay * w1v + m;
            m = ax * w0v + m;
            m = __builtin_elementwise_max(m, zero);
            accv += m;
        };

        int t = rs;
        for (; t + 3 < re; t += 4) {
            uint2 r0 = recs[t];
            uint2 r1 = recs[t + 1];
            uint2 r2 = recs[t + 2];
            uint2 r3 = recs[t + 3];
            uint u0 = *(const uint*)(xb + (size_t)r0.x * 128 + j);
            uint u1 = *(const uint*)(xb + (size_t)r1.x * 128 + j);
            uint u2 = *(const uint*)(xb + (size_t)r2.x * 128 + j);
            uint u3 = *(const uint*)(xb + (size_t)r3.x * 128 + j);
            proc(r0, u0); proc(r1, u1); proc(r2, u2); proc(r3, u3);
        }
        for (; t < re; t++) {
            uint2 r0 = recs[t];
            uint u0 = *(const uint*)(xb + (size_t)r0.x * 128 + j);
            proc(r0, u0);
        }

        // residual
        {
            uint u = *(const uint*)(xb + (size_t)node * 128 + j);
            union { uint i; float f; } lo, hi;
            lo.i = u << 16;
            hi.i = u & 0xFFFF0000u;
            f2v xv = {lo.f, hi.f};
            accv += xv;
        }
        uint up = (uint)f2bf(accv.x) | ((uint)f2bf(accv.y) << 16);
        ((uint*)tb)[(size_t)node * 64 + lane] = up;
    } else {
        float w0 = We[lane], w1 = We[64 + lane], bb = be[lane];
        float acc = 0.f;

        auto proc = [&](uint2 r, ushort u) {
            float ax = bf2f((ushort)(r.y & 0xFFFF));
            float ay = bf2f((ushort)(r.y >> 16));
            float m = bf2f(u) + bb;
            m = ay * w1 + m;
            m = ax * w0 + m;
            acc += fmaxf(m, 0.f);
        };

        int t = rs;
        for (; t + 3 < re; t += 4) {
            uint2 r0 = recs[t];
            uint2 r1 = recs[t + 1];
            uint2 r2 = recs[t + 2];
            uint2 r3 = recs[t + 3];
            ushort u0 = xb[(size_t)r0.x * 64 + lane];
            ushort u1 = xb[(size_t)r1.x * 64 + lane];
            ushort u2 = xb[(size_t)r2.x * 64 + lane];
            ushort u3 = xb[(size_t)r3.x * 64 + lane];
            proc(r0, u0); proc(r1, u1); proc(r2, u2); proc(r3, u3);
        }
        for (; t < re; t++) {
            uint2 r0 = recs[t];
            ushort u0 = xb[(size_t)r0.x * 64 + lane];
            proc(r0, u0);
        }
        acc += bf2f(xb[(size_t)node * 64 + lane]);
        tb[(size_t)node * 64 + lane] = f2bf(acc);
    }
}

// ---------------- node transform via MFMA: hb = leaky(tb @ Wn + bn), bf16 ----------------

template <int K>
__global__ __launch_bounds__(256) void gine_transform_mfma(const ushort* __restrict__ tb,
                                                           const ushort* __restrict__ wnT,
                                                           const float* __restrict__ bn,
                                                           ushort* __restrict__ hb) {
    int wave = threadIdx.x >> 6;
    int lane = threadIdx.x & 63;
    int m0 = blockIdx.x * 64 + wave * 16;
    int l15 = lane & 15;
    int kgrp = (lane >> 4) * 8;

    const ushort* aptr = tb + (size_t)(m0 + l15) * K + kgrp;

    f32x4 acc[8];
#pragma unroll
    for (int nt = 0; nt < 8; nt++) {
        float b = bn[nt * 16 + l15];
        acc[nt] = {b, b, b, b};
    }

#pragma unroll
    for (int kk = 0; kk < K / 32; kk++) {
        bf16x8 a = *(const bf16x8*)(aptr + kk * 32);
#pragma unroll
        for (int nt = 0; nt < 8; nt++) {
            bf16x8 bfrag = *(const bf16x8*)(wnT + (size_t)(nt * 16 + l15) * K + kk * 32 + kgrp);
            acc[nt] = __builtin_amdgcn_mfma_f32_16x16x32_bf16(a, bfrag, acc[nt], 0, 0, 0);
        }
    }

    int rbase = m0 + (lane >> 4) * 4;
#pragma unroll
    for (int nt = 0; nt < 8; nt++) {
#pragma unroll
        for (int r = 0; r < 4; r++) {
            int nd = rbase + r;
            if (nd < N_NODES)
                hb[(size_t)nd * HID + nt * 16 + l15] = f2bf(leaky(acc[nt][r]));
        }
    }
}

// ---------------- pooling: one wave per 64-node slab; batch sorted -> wave-uniform graph id ----------------
#define POOL_NPW 64
__global__ __launch_bounds__(256) void pool_kernel(const ushort* __restrict__ h,
                                                   const int* __restrict__ batch,
                                                   float* __restrict__ pooled) {
    int wid = (blockIdx.x * 256 + (int)threadIdx.x) >> 6;
    int lane = threadIdx.x & 63;
    int n0 = wid * POOL_NPW;
    if (n0 >= N_NODES) return;
    int n1 = n0 + POOL_NPW; if (n1 > N_NODES) n1 = N_NODES;

    int j = lane * 2;
    f2v acc = {0.f, 0.f};
    int g = __builtin_amdgcn_readfirstlane(batch[n0]);
    for (int i = n0; i < n1; i++) {
        int bg = __builtin_amdgcn_readfirstlane(batch[i]);
        if (bg != g) {
            atomicAdd(&pooled[g * HID + j], acc.x);
            atomicAdd(&pooled[g * HID + j + 1], acc.y);
            acc.x = 0.f; acc.y = 0.f;
            g = bg;
        }
        uint u = *(const uint*)(h + (size_t)i * HID + j);
        union { uint i; float f; } lo, hi;
        lo.i = u << 16;
        hi.i = u & 0xFFFF0000u;
        acc.x += lo.f;
        acc.y += hi.f;
    }
    atomicAdd(&pooled[g * HID + j], acc.x);
    atomicAdd(&pooled[g * HID + j + 1], acc.y);
}

// ---------------- head MLP ----------------

__global__ __launch_bounds__(256) void head_kernel(const float* __restrict__ pooled,
                                                   const float* __restrict__ Wh0,
                                                   const float* __restrict__ bh0,
                                                   const float* __restrict__ Wh1,
                                                   const float* __restrict__ bh1,
                                                   float* __restrict__ out) {
    __shared__ float p[HID];
    __shared__ float hid[HEAD_H];
    int g = blockIdx.x;
    int t = threadIdx.x;
    if (t < HID) p[t] = pooled[g * HID + t];
    __syncthreads();
    float acc = bh0[t];
    for (int k = 0; k < HID; k++) acc += p[k] * Wh0[k * HEAD_H + t];
    hid[t] = leaky(acc);
    __syncthreads();
    if (t < OUT_F) {
        float o = bh1[t];
        for (int k = 0; k < HEAD_H; k++) o += hid[k] * Wh1[k * OUT_F + t];
        out[g * OUT_F + t] = o;
    }
}

extern "C" void kernel_launch(void* const* d_in, const int* in_sizes, int n_in,
                              void* d_out, int out_size, void* d_ws, size_t ws_size,
                              hipStream_t stream) {
    const float* x     = (const float*)d_in[0];
    const int*   ei    = (const int*)d_in[1];
    const float* ea    = (const float*)d_in[2];
    const int*   batch = (const int*)d_in[3];
    const float* We0 = (const float*)d_in[4];
    const float* be0 = (const float*)d_in[5];
    const float* Wn0 = (const float*)d_in[6];
    const float* bn0 = (const float*)d_in[7];
    const float* We1 = (const float*)d_in[8];
    const float* be1 = (const float*)d_in[9];
    const float* Wn1 = (const float*)d_in[10];
    const float* bn1 = (const float*)d_in[11];
    const float* We2 = (const float*)d_in[12];
    const float* be2 = (const float*)d_in[13];
    const float* Wn2 = (const float*)d_in[14];
    const float* bn2 = (const float*)d_in[15];
    const float* Wh0 = (const float*)d_in[16];
    const float* bh0 = (const float*)d_in[17];
    const float* Wh1 = (const float*)d_in[18];
    const float* bh1 = (const float*)d_in[19];

    const int* src = ei;
    const int* dst = ei + N_EDGES;

    char* ws = (char*)d_ws;
    size_t o = 0;
    uint2*  recs1 = (uint2*)(ws + o); o += (size_t)N_EDGES * 8;           // 12.8 MB
    uint2*  recs2 = (uint2*)(ws + o); o += (size_t)N_EDGES * 8;           // 12.8 MB
    ushort* xb0  = (ushort*)(ws + o); o += (size_t)N_NODES * 64 * 2;      // 12.8 MB
    ushort* tbuf = (ushort*)(ws + o); o += (size_t)N_NODES * 128 * 2;     // 25.6 MB
    ushort* hbuf = (ushort*)(ws + o); o += (size_t)N_NODES * 128 * 2;     // 25.6 MB
    int*    rowptr = (int*)(ws + o);  o += 400128;
    int*    cnt    = (int*)(ws + o);  o += 400128;
    int*    bsum   = (int*)(ws + o);  o += 4096;
    int*    bcur   = (int*)(ws + o);  o += 4096;
    ushort* wnT0 = (ushort*)(ws + o); o += 128 * 64 * 2;
    ushort* wnT1 = (ushort*)(ws + o); o += 128 * 128 * 2;
    ushort* wnT2 = (ushort*)(ws + o); o += 128 * 128 * 2;
    float*  pooled = (float*)(ws + o); o += (size_t)N_GRAPHS * HID * 4;

    // --- cast x to bf16; prep transposed bf16 weights ---
    cast_kernel<<<(N_NODES * F_IN / 2 + 255) / 256, 256, 0, stream>>>(x, xb0, N_NODES * F_IN / 2);
    prep_wnT<<<160, 256, 0, stream>>>(Wn0, Wn1, Wn2, wnT0, wnT1, wnT2);

    // --- CSR build (by dst): hist -> rowptr -> two-phase bin/order sort ---
    hipMemsetAsync(cnt, 0, N_NODES * sizeof(int), stream);
    hist_kernel<<<(N_EDGES / 4 + 255) / 256, 256, 0, stream>>>(dst, cnt);
    scan_sums<<<NB_SCAN, 256, 0, stream>>>(cnt, bsum);
    scan_offsets<<<1, 128, 0, stream>>>(bsum, rowptr);
    scan_final<<<NB_SCAN, 256, 0, stream>>>(cnt, bsum, rowptr);
    init_bcur<<<1, 128, 0, stream>>>(rowptr, bcur);
    bin_kernel<<<NCHUNKS, 256, 0, stream>>>(src, dst, (const float2*)ea, bcur, recs1);
    order_kernel<<<NBK, 256, 0, stream>>>(recs1, rowptr, recs2);

    const int GATHER_BLOCKS = (N_NODES * 64 + 255) / 256;   // 25000
    const int TRANS_BLOCKS  = (N_NODES + 63) / 64;          // 1563

    // --- layer 0 (64 -> 128) ---
    gine_gather<64><<<GATHER_BLOCKS, 256, 0, stream>>>(xb0, recs2, rowptr, We0, be0, tbuf);
    gine_transform_mfma<64><<<TRANS_BLOCKS, 256, 0, stream>>>(tbuf, wnT0, bn0, hbuf);

    // --- layer 1 (128 -> 128) ---
    gine_gather<128><<<GATHER_BLOCKS, 256, 0, stream>>>(hbuf, recs2, rowptr, We1, be1, tbuf);
    gine_transform_mfma<128><<<TRANS_BLOCKS, 256, 0, stream>>>(tbuf, wnT1, bn1, hbuf);

    // --- layer 2 (128 -> 128) ---
    gine_gather<128><<<GATHER_BLOCKS, 256, 0, stream>>>(hbuf, recs2, rowptr, We2, be2, tbuf);
    gine_transform_mfma<128><<<TRANS_BLOCKS, 256, 0, stream>>>(tbuf, wnT2, bn2, hbuf);

    // --- pool + head ---
    hipMemsetAsync(pooled, 0, (size_t)N_GRAPHS * HID * sizeof(float), stream);
    pool_kernel<<<(N_NODES / POOL_NPW + 3) / 4, 256, 0, stream>>>(hbuf, batch, pooled);
    head_kernel<<<N_GRAPHS, 256, 0, stream>>>(pooled, Wh0, bh0, Wh1, bh1, (float*)d_out);
}

// Round 8
// 393.817 us; speedup vs baseline: 3.4064x; 1.1556x over previous
//
#include <hip/hip_runtime.h>
#include <hip/hip_bf16.h>

#define N_NODES 100000
#define N_EDGES 1600000
#define F_IN 64
#define HID 128
#define HEAD_H 256
#define OUT_F 32
#define N_GRAPHS 512
#define NBK 98       // coarse buckets (dst >> 10)
#define BCHUNK 4096  // edges per bin-kernel block
#define NCHUNKS ((N_EDGES + BCHUNK - 1) / BCHUNK)  // 391

typedef float f2v __attribute__((ext_vector_type(2)));
typedef short bf16x8 __attribute__((ext_vector_type(8)));
typedef float f32x4 __attribute__((ext_vector_type(4)));

__device__ __forceinline__ float leaky(float v) {
    return v >= 0.f ? v : 0.01f * v;
}

__device__ __forceinline__ float bf2f(ushort u) {
    union { uint i; float f; } c; c.i = ((uint)u) << 16; return c.f;
}

__device__ __forceinline__ ushort f2bf(float f) {
    union { float f; uint i; } c; c.f = f;
    uint r = c.i + 0x7FFF + ((c.i >> 16) & 1);
    return (ushort)(r >> 16);
}

// ---------------- cast x -> bf16 ----------------
__global__ __launch_bounds__(256) void cast_kernel(const float* __restrict__ x,
                                                   ushort* __restrict__ xb, int n2) {
    int i = blockIdx.x * 256 + threadIdx.x;  // handles 2 elems
    if (i < n2) {
        float2 v = ((const float2*)x)[i];
        uint u = (uint)f2bf(v.x) | ((uint)f2bf(v.y) << 16);
        ((uint*)xb)[i] = u;
    }
}

// ---------------- weight prep: WnT[j][k] = bf16(Wn[k][j]) for 3 layers ----------------
__global__ __launch_bounds__(256) void prep_wnT(const float* __restrict__ Wn0,
                                                const float* __restrict__ Wn1,
                                                const float* __restrict__ Wn2,
                                                ushort* __restrict__ w0T,
                                                ushort* __restrict__ w1T,
                                                ushort* __restrict__ w2T) {
    int id = blockIdx.x * 256 + threadIdx.x;
    if (id < 128 * 64) {
        int j = id / 64, k = id % 64;
        w0T[id] = f2bf(Wn0[k * 128 + j]);
    } else if (id < 128 * 64 + 128 * 128) {
        int t = id - 128 * 64; int j = t / 128, k = t % 128;
        w1T[t] = f2bf(Wn1[k * 128 + j]);
    } else if (id < 128 * 64 + 2 * 128 * 128) {
        int t = id - 128 * 64 - 128 * 128; int j = t / 128, k = t % 128;
        w2T[t] = f2bf(Wn2[k * 128 + j]);
    }
}

// ---------------- bucket-level CSR build (no per-node global atomics) ----------------

// per-chunk LDS histogram over 98 buckets -> 98 global atomics per chunk
__global__ __launch_bounds__(256) void bucket_hist(const int* __restrict__ dst,
                                                   int* __restrict__ cnt98) {
    __shared__ int h[NBK];
    int tid = threadIdx.x;
    if (tid < NBK) h[tid] = 0;
    __syncthreads();
    int e0 = blockIdx.x * BCHUNK;
    int nn = N_EDGES - e0; if (nn > BCHUNK) nn = BCHUNK;
    for (int i = tid; i < nn; i += 256) {
        atomicAdd(&h[dst[e0 + i] >> 10], 1);
    }
    __syncthreads();
    if (tid < NBK && h[tid] > 0) atomicAdd(&cnt98[tid], h[tid]);
}

// scan 98 bucket counts -> bucket bases (bbase, immutable) + bin cursors (bcur)
__global__ __launch_bounds__(128) void bucket_scan(const int* __restrict__ cnt98,
                                                   int* __restrict__ bbase,
                                                   int* __restrict__ bcur,
                                                   int* __restrict__ rowptr) {
    __shared__ int sd[128];
    int t = threadIdx.x;
    int v = (t < NBK) ? cnt98[t] : 0;
    sd[t] = v;
    __syncthreads();
    for (int off = 1; off < 128; off <<= 1) {
        int u = (t >= off) ? sd[t - off] : 0;
        __syncthreads();
        sd[t] += u;
        __syncthreads();
    }
    if (t < NBK) {
        int ex = sd[t] - v;
        bbase[t] = ex;
        bcur[t] = ex;
    }
    if (t == 0) {
        bbase[NBK] = N_EDGES;
        rowptr[N_NODES] = N_EDGES;
    }
}

// ---------------- pass 1: bin edges by dst>>10 into bucket regions of recs1 ----------------
// record: x = src | (dloc<<22), y = packed bf16 edge attrs. Order within bucket arbitrary.
__global__ __launch_bounds__(256) void bin_kernel(const int* __restrict__ src,
                                                  const int* __restrict__ dst,
                                                  const float2* __restrict__ ea,
                                                  int* __restrict__ bcur,
                                                  uint2* __restrict__ recs1) {
    __shared__ int hist[NBK], tmp[NBK], offs[NBK], cur[NBK], gbase[NBK];
    __shared__ uint2 stage[BCHUNK];
    __shared__ unsigned char sbid[BCHUNK];

    int tid = threadIdx.x;
    int e0 = blockIdx.x * BCHUNK;
    int nn = N_EDGES - e0; if (nn > BCHUNK) nn = BCHUNK;

    if (tid < NBK) hist[tid] = 0;
    __syncthreads();

    // phase A: histogram over this chunk
    for (int i = tid; i < nn; i += 256) {
        atomicAdd(&hist[dst[e0 + i] >> 10], 1);
    }
    __syncthreads();

    // scan hist -> offs (exclusive), Hillis-Steele over NBK entries
    if (tid < NBK) tmp[tid] = hist[tid];
    __syncthreads();
    for (int off = 1; off < NBK; off <<= 1) {
        int u = (tid < NBK && tid >= off) ? tmp[tid - off] : 0;
        __syncthreads();
        if (tid < NBK) tmp[tid] += u;
        __syncthreads();
    }
    if (tid < NBK) {
        int ex = tmp[tid] - hist[tid];
        offs[tid] = ex;
        cur[tid] = ex;
        gbase[tid] = (hist[tid] > 0) ? atomicAdd(&bcur[tid], hist[tid]) : 0;
    }
    __syncthreads();

    // phase B: place records into LDS, bucket-sorted
    for (int i = tid; i < nn; i += 256) {
        int e = e0 + i;
        int d = dst[e];
        int b = d >> 10;
        int dloc = d & 1023;
        float2 a = ea[e];
        uint2 r;
        r.x = (uint)src[e] | ((uint)dloc << 22);
        r.y = (uint)f2bf(a.x) | ((uint)f2bf(a.y) << 16);
        int pos = atomicAdd(&cur[b], 1);
        stage[pos] = r;
        sbid[pos] = (unsigned char)b;
    }
    __syncthreads();

    // phase C: flush contiguous per-bucket runs
    for (int i = tid; i < nn; i += 256) {
        int b = sbid[i];
        recs1[gbase[b] + (i - offs[b])] = stage[i];
    }
}

// ---------------- pass 2: build per-node rowptr (LDS) + order records into CSR slots ----------------
__global__ __launch_bounds__(256) void order_kernel(const uint2* __restrict__ recs1,
                                                    const int* __restrict__ bbase,
                                                    int* __restrict__ rowptr,
                                                    uint2* __restrict__ recs2) {
    __shared__ int h[1024];
    __shared__ int ssum[256];
    int b = blockIdx.x;
    int tid = threadIdx.x;
    int base = bbase[b];
    int end = bbase[b + 1];

    for (int i = tid; i < 1024; i += 256) h[i] = 0;
    __syncthreads();

    // LDS histogram of node-local ids over this bucket's region
    for (int t = base + tid; t < end; t += 256) {
        atomicAdd(&h[recs1[t].x >> 22], 1);
    }
    __syncthreads();

    // scan 1024 in LDS: thread owns 4 entries + 256-ladder
    int i4 = tid * 4;
    int a0 = h[i4], a1 = h[i4 + 1], a2 = h[i4 + 2], a3 = h[i4 + 3];
    int s = a0 + a1 + a2 + a3;
    ssum[tid] = s;
    __syncthreads();
    for (int off = 1; off < 256; off <<= 1) {
        int u = (tid >= off) ? ssum[tid - off] : 0;
        __syncthreads();
        ssum[tid] += u;
        __syncthreads();
    }
    int pre = base + ssum[tid] - s;  // absolute exclusive prefix
    int c0 = pre, c1 = pre + a0, c2 = c1 + a1, c3 = c2 + a2;
    h[i4] = c0; h[i4 + 1] = c1; h[i4 + 2] = c2; h[i4 + 3] = c3;

    // write rowptr for this bucket's nodes (coalesced)
    int n = (b << 10) + i4;
    if (n + 4 <= N_NODES) {
        *(int4*)(rowptr + n) = make_int4(c0, c1, c2, c3);
    } else {
        if (n + 0 < N_NODES) rowptr[n + 0] = c0;
        if (n + 1 < N_NODES) rowptr[n + 1] = c1;
        if (n + 2 < N_NODES) rowptr[n + 2] = c2;
        if (n + 3 < N_NODES) rowptr[n + 3] = c3;
    }
    __syncthreads();

    // place records into exact CSR slots
    for (int t = base + tid; t < end; t += 256) {
        uint2 r = recs1[t];
        int pos = atomicAdd(&h[r.x >> 22], 1);
        recs2[pos] = make_uint2(r.x & 0x3FFFFFu, r.y);
    }
}

// ---------------- GINE edge gather (one wave per node), bf16 features ----------------

template <int D>
__global__ __launch_bounds__(256) void gine_gather(const ushort* __restrict__ xb,
                                                   const uint2* __restrict__ recs,
                                                   const int* __restrict__ rowptr,
                                                   const float* __restrict__ We,
                                                   const float* __restrict__ be,
                                                   ushort* __restrict__ tb) {
    int node = (blockIdx.x * 256 + (int)threadIdx.x) >> 6;
    int lane = threadIdx.x & 63;
    if (node >= N_NODES) return;

    int rs = __builtin_amdgcn_readfirstlane(rowptr[node]);
    int re = __builtin_amdgcn_readfirstlane(rowptr[node + 1]);

    if constexpr (D == 128) {
        int j = lane * 2;
        f2v w0v = {We[j], We[j + 1]};
        f2v w1v = {We[128 + j], We[128 + j + 1]};
        f2v bbv = {be[j], be[j + 1]};
        f2v accv = {0.f, 0.f};
        const f2v zero = {0.f, 0.f};

        auto proc = [&](uint2 r, uint u) {
            float ax = bf2f((ushort)(r.y & 0xFFFF));
            float ay = bf2f((ushort)(r.y >> 16));
            union { uint i; float f; } lo, hi;
            lo.i = u << 16;
            hi.i = u & 0xFFFF0000u;
            f2v xv = {lo.f, hi.f};
            f2v m = xv + bbv;
            m = ay * w1v + m;
            m = ax * w0v + m;
            m = __builtin_elementwise_max(m, zero);
            accv += m;
        };

        int t = rs;
        for (; t + 7 < re; t += 8) {
            uint2 r0 = recs[t];
            uint2 r1 = recs[t + 1];
            uint2 r2 = recs[t + 2];
            uint2 r3 = recs[t + 3];
            uint2 r4 = recs[t + 4];
            uint2 r5 = recs[t + 5];
            uint2 r6 = recs[t + 6];
            uint2 r7 = recs[t + 7];
            uint u0 = *(const uint*)(xb + (size_t)r0.x * 128 + j);
            uint u1 = *(const uint*)(xb + (size_t)r1.x * 128 + j);
            uint u2 = *(const uint*)(xb + (size_t)r2.x * 128 + j);
            uint u3 = *(const uint*)(xb + (size_t)r3.x * 128 + j);
            uint u4 = *(const uint*)(xb + (size_t)r4.x * 128 + j);
            uint u5 = *(const uint*)(xb + (size_t)r5.x * 128 + j);
            uint u6 = *(const uint*)(xb + (size_t)r6.x * 128 + j);
            uint u7 = *(const uint*)(xb + (size_t)r7.x * 128 + j);
            proc(r0, u0); proc(r1, u1); proc(r2, u2); proc(r3, u3);
            proc(r4, u4); proc(r5, u5); proc(r6, u6); proc(r7, u7);
        }
        for (; t + 3 < re; t += 4) {
            uint2 r0 = recs[t];
            uint2 r1 = recs[t + 1];
            uint2 r2 = recs[t + 2];
            uint2 r3 = recs[t + 3];
            uint u0 = *(const uint*)(xb + (size_t)r0.x * 128 + j);
            uint u1 = *(const uint*)(xb + (size_t)r1.x * 128 + j);
            uint u2 = *(const uint*)(xb + (size_t)r2.x * 128 + j);
            uint u3 = *(const uint*)(xb + (size_t)r3.x * 128 + j);
            proc(r0, u0); proc(r1, u1); proc(r2, u2); proc(r3, u3);
        }
        for (; t < re; t++) {
            uint2 r0 = recs[t];
            uint u0 = *(const uint*)(xb + (size_t)r0.x * 128 + j);
            proc(r0, u0);
        }

        // residual
        {
            uint u = *(const uint*)(xb + (size_t)node * 128 + j);
            union { uint i; float f; } lo, hi;
            lo.i = u << 16;
            hi.i = u & 0xFFFF0000u;
            f2v xv = {lo.f, hi.f};
            accv += xv;
        }
        uint up = (uint)f2bf(accv.x) | ((uint)f2bf(accv.y) << 16);
        ((uint*)tb)[(size_t)node * 64 + lane] = up;
    } else {
        float w0 = We[lane], w1 = We[64 + lane], bb = be[lane];
        float acc = 0.f;

        auto proc = [&](uint2 r, ushort u) {
            float ax = bf2f((ushort)(r.y & 0xFFFF));
            float ay = bf2f((ushort)(r.y >> 16));
            float m = bf2f(u) + bb;
            m = ay * w1 + m;
            m = ax * w0 + m;
            acc += fmaxf(m, 0.f);
        };

        int t = rs;
        for (; t + 7 < re; t += 8) {
            uint2 r0 = recs[t];
            uint2 r1 = recs[t + 1];
            uint2 r2 = recs[t + 2];
            uint2 r3 = recs[t + 3];
            uint2 r4 = recs[t + 4];
            uint2 r5 = recs[t + 5];
            uint2 r6 = recs[t + 6];
            uint2 r7 = recs[t + 7];
            ushort u0 = xb[(size_t)r0.x * 64 + lane];
            ushort u1 = xb[(size_t)r1.x * 64 + lane];
            ushort u2 = xb[(size_t)r2.x * 64 + lane];
            ushort u3 = xb[(size_t)r3.x * 64 + lane];
            ushort u4 = xb[(size_t)r4.x * 64 + lane];
            ushort u5 = xb[(size_t)r5.x * 64 + lane];
            ushort u6 = xb[(size_t)r6.x * 64 + lane];
            ushort u7 = xb[(size_t)r7.x * 64 + lane];
            proc(r0, u0); proc(r1, u1); proc(r2, u2); proc(r3, u3);
            proc(r4, u4); proc(r5, u5); proc(r6, u6); proc(r7, u7);
        }
        for (; t + 3 < re; t += 4) {
            uint2 r0 = recs[t];
            uint2 r1 = recs[t + 1];
            uint2 r2 = recs[t + 2];
            uint2 r3 = recs[t + 3];
            ushort u0 = xb[(size_t)r0.x * 64 + lane];
            ushort u1 = xb[(size_t)r1.x * 64 + lane];
            ushort u2 = xb[(size_t)r2.x * 64 + lane];
            ushort u3 = xb[(size_t)r3.x * 64 + lane];
            proc(r0, u0); proc(r1, u1); proc(r2, u2); proc(r3, u3);
        }
        for (; t < re; t++) {
            uint2 r0 = recs[t];
            ushort u0 = xb[(size_t)r0.x * 64 + lane];
            proc(r0, u0);
        }
        acc += bf2f(xb[(size_t)node * 64 + lane]);
        tb[(size_t)node * 64 + lane] = f2bf(acc);
    }
}

// ---------------- node transform via MFMA: hb = leaky(tb @ Wn + bn), bf16 ----------------

template <int K>
__global__ __launch_bounds__(256) void gine_transform_mfma(const ushort* __restrict__ tb,
                                                           const ushort* __restrict__ wnT,
                                                           const float* __restrict__ bn,
                                                           ushort* __restrict__ hb) {
    int wave = threadIdx.x >> 6;
    int lane = threadIdx.x & 63;
    int m0 = blockIdx.x * 64 + wave * 16;
    int l15 = lane & 15;
    int kgrp = (lane >> 4) * 8;

    const ushort* aptr = tb + (size_t)(m0 + l15) * K + kgrp;

    f32x4 acc[8];
#pragma unroll
    for (int nt = 0; nt < 8; nt++) {
        float b = bn[nt * 16 + l15];
        acc[nt] = {b, b, b, b};
    }

#pragma unroll
    for (int kk = 0; kk < K / 32; kk++) {
        bf16x8 a = *(const bf16x8*)(aptr + kk * 32);
#pragma unroll
        for (int nt = 0; nt < 8; nt++) {
            bf16x8 bfrag = *(const bf16x8*)(wnT + (size_t)(nt * 16 + l15) * K + kk * 32 + kgrp);
            acc[nt] = __builtin_amdgcn_mfma_f32_16x16x32_bf16(a, bfrag, acc[nt], 0, 0, 0);
        }
    }

    int rbase = m0 + (lane >> 4) * 4;
#pragma unroll
    for (int nt = 0; nt < 8; nt++) {
#pragma unroll
        for (int r = 0; r < 4; r++) {
            int nd = rbase + r;
            if (nd < N_NODES)
                hb[(size_t)nd * HID + nt * 16 + l15] = f2bf(leaky(acc[nt][r]));
        }
    }
}

// ---------------- pooling: one wave per 64-node slab; batch sorted -> wave-uniform graph id ----------------
#define POOL_NPW 64
__global__ __launch_bounds__(256) void pool_kernel(const ushort* __restrict__ h,
                                                   const int* __restrict__ batch,
                                                   float* __restrict__ pooled) {
    int wid = (blockIdx.x * 256 + (int)threadIdx.x) >> 6;
    int lane = threadIdx.x & 63;
    int n0 = wid * POOL_NPW;
    if (n0 >= N_NODES) return;
    int n1 = n0 + POOL_NPW; if (n1 > N_NODES) n1 = N_NODES;

    int j = lane * 2;
    f2v acc = {0.f, 0.f};
    int g = __builtin_amdgcn_readfirstlane(batch[n0]);
    for (int i = n0; i < n1; i++) {
        int bg = __builtin_amdgcn_readfirstlane(batch[i]);
        if (bg != g) {
            atomicAdd(&pooled[g * HID + j], acc.x);
            atomicAdd(&pooled[g * HID + j + 1], acc.y);
            acc.x = 0.f; acc.y = 0.f;
            g = bg;
        }
        uint u = *(const uint*)(h + (size_t)i * HID + j);
        union { uint i; float f; } lo, hi;
        lo.i = u << 16;
        hi.i = u & 0xFFFF0000u;
        acc.x += lo.f;
        acc.y += hi.f;
    }
    atomicAdd(&pooled[g * HID + j], acc.x);
    atomicAdd(&pooled[g * HID + j + 1], acc.y);
}

// ---------------- head MLP ----------------

__global__ __launch_bounds__(256) void head_kernel(const float* __restrict__ pooled,
                                                   const float* __restrict__ Wh0,
                                                   const float* __restrict__ bh0,
                                                   const float* __restrict__ Wh1,
                                                   const float* __restrict__ bh1,
                                                   float* __restrict__ out) {
    __shared__ float p[HID];
    __shared__ float hid[HEAD_H];
    int g = blockIdx.x;
    int t = threadIdx.x;
    if (t < HID) p[t] = pooled[g * HID + t];
    __syncthreads();
    float acc = bh0[t];
    for (int k = 0; k < HID; k++) acc += p[k] * Wh0[k * HEAD_H + t];
    hid[t] = leaky(acc);
    __syncthreads();
    if (t < OUT_F) {
        float o = bh1[t];
        for (int k = 0; k < HEAD_H; k++) o += hid[k] * Wh1[k * OUT_F + t];
        out[g * OUT_F + t] = o;
    }
}

extern "C" void kernel_launch(void* const* d_in, const int* in_sizes, int n_in,
                              void* d_out, int out_size, void* d_ws, size_t ws_size,
                              hipStream_t stream) {
    const float* x     = (const float*)d_in[0];
    const int*   ei    = (const int*)d_in[1];
    const float* ea    = (const float*)d_in[2];
    const int*   batch = (const int*)d_in[3];
    const float* We0 = (const float*)d_in[4];
    const float* be0 = (const float*)d_in[5];
    const float* Wn0 = (const float*)d_in[6];
    const float* bn0 = (const float*)d_in[7];
    const float* We1 = (const float*)d_in[8];
    const float* be1 = (const float*)d_in[9];
    const float* Wn1 = (const float*)d_in[10];
    const float* bn1 = (const float*)d_in[11];
    const float* We2 = (const float*)d_in[12];
    const float* be2 = (const float*)d_in[13];
    const float* Wn2 = (const float*)d_in[14];
    const float* bn2 = (const float*)d_in[15];
    const float* Wh0 = (const float*)d_in[16];
    const float* bh0 = (const float*)d_in[17];
    const float* Wh1 = (const float*)d_in[18];
    const float* bh1 = (const float*)d_in[19];

    const int* src = ei;
    const int* dst = ei + N_EDGES;

    char* ws = (char*)d_ws;
    size_t o = 0;
    uint2*  recs1 = (uint2*)(ws + o); o += (size_t)N_EDGES * 8;           // 12.8 MB
    uint2*  recs2 = (uint2*)(ws + o); o += (size_t)N_EDGES * 8;           // 12.8 MB
    ushort* xb0  = (ushort*)(ws + o); o += (size_t)N_NODES * 64 * 2;      // 12.8 MB
    ushort* tbuf = (ushort*)(ws + o); o += (size_t)N_NODES * 128 * 2;     // 25.6 MB
    ushort* hbuf = (ushort*)(ws + o); o += (size_t)N_NODES * 128 * 2;     // 25.6 MB
    int*    rowptr = (int*)(ws + o);  o += 400128;
    int*    cnt98  = (int*)(ws + o);  o += 4096;
    int*    bbase  = (int*)(ws + o);  o += 4096;
    int*    bcur   = (int*)(ws + o);  o += 4096;
    ushort* wnT0 = (ushort*)(ws + o); o += 128 * 64 * 2;
    ushort* wnT1 = (ushort*)(ws + o); o += 128 * 128 * 2;
    ushort* wnT2 = (ushort*)(ws + o); o += 128 * 128 * 2;
    float*  pooled = (float*)(ws + o); o += (size_t)N_GRAPHS * HID * 4;

    // --- cast x to bf16; prep transposed bf16 weights ---
    cast_kernel<<<(N_NODES * F_IN / 2 + 255) / 256, 256, 0, stream>>>(x, xb0, N_NODES * F_IN / 2);
    prep_wnT<<<160, 256, 0, stream>>>(Wn0, Wn1, Wn2, wnT0, wnT1, wnT2);

    // --- CSR build: bucket hist -> bucket scan -> bin -> order (rowptr built in LDS) ---
    hipMemsetAsync(cnt98, 0, NBK * sizeof(int), stream);
    bucket_hist<<<NCHUNKS, 256, 0, stream>>>(dst, cnt98);
    bucket_scan<<<1, 128, 0, stream>>>(cnt98, bbase, bcur, rowptr);
    bin_kernel<<<NCHUNKS, 256, 0, stream>>>(src, dst, (const float2*)ea, bcur, recs1);
    order_kernel<<<NBK, 256, 0, stream>>>(recs1, bbase, rowptr, recs2);

    const int GATHER_BLOCKS = (N_NODES * 64 + 255) / 256;   // 25000
    const int TRANS_BLOCKS  = (N_NODES + 63) / 64;          // 1563

    // --- layer 0 (64 -> 128) ---
    gine_gather<64><<<GATHER_BLOCKS, 256, 0, stream>>>(xb0, recs2, rowptr, We0, be0, tbuf);
    gine_transform_mfma<64><<<TRANS_BLOCKS, 256, 0, stream>>>(tbuf, wnT0, bn0, hbuf);

    // --- layer 1 (128 -> 128) ---
    gine_gather<128><<<GATHER_BLOCKS, 256, 0, stream>>>(hbuf, recs2, rowptr, We1, be1, tbuf);
    gine_transform_mfma<128><<<TRANS_BLOCKS, 256, 0, stream>>>(tbuf, wnT1, bn1, hbuf);

    // --- layer 2 (128 -> 128) ---
    gine_gather<128><<<GATHER_BLOCKS, 256, 0, stream>>>(hbuf, recs2, rowptr, We2, be2, tbuf);
    gine_transform_mfma<128><<<TRANS_BLOCKS, 256, 0, stream>>>(tbuf, wnT2, bn2, hbuf);

    // --- pool + head ---
    hipMemsetAsync(pooled, 0, (size_t)N_GRAPHS * HID * sizeof(float), stream);
    pool_kernel<<<(N_NODES / POOL_NPW + 3) / 4, 256, 0, stream>>>(hbuf, batch, pooled);
    head_kernel<<<N_GRAPHS, 256, 0, stream>>>(pooled, Wh0, bh0, Wh1, bh1, (float*)d_out);
}